// Round 6
// baseline (22255.884 us; speedup 1.0000x reference)
//
#include <hip/hip_runtime.h>
#include <math.h>

#define NLATg 181
#define NLONg 360
#define PIXg  65160        // 181*360
#define EMBg  256
#define MHIDg 512
#define PLANEg 8386816     // 181*46336
#define PKSTR 184          // padded k-extent stride in Pa/Ps (mult of 8, zero-padded)
#define PMSTR2 33304       // 181*184, per-m stride in Pa/Ps

#define FLAG_GELU 1
#define FLAG_ACC  2
#define FLAG_F32  4
#define FLAG_BF16 8

typedef unsigned short u16;
typedef unsigned int   u32;
typedef __attribute__((ext_vector_type(8))) short bf16x8;
typedef __attribute__((ext_vector_type(4))) float f32x4;

__device__ __forceinline__ float gelu_f(float x) {
    return 0.5f * x * (1.0f + erff(x * 0.70710678118654752440f));
}

// fp32 -> (hi, lo) truncated bf16 pair: v ~= hi + lo with ~2^-16 relative error.
__device__ __forceinline__ void split_f(float v, u16& h, u16& l) {
    u32 u = __float_as_uint(v);
    h = (u16)(u >> 16);
    float hf = __uint_as_float(u & 0xFFFF0000u);
    l = (u16)(__float_as_uint(v - hf) >> 16);
}

// async global->LDS, 16B per lane; LDS dest = wave-uniform base + lane*16 (HW rule)
__device__ __forceinline__ void glds16(const u16* g, u16* l) {
    __builtin_amdgcn_global_load_lds((const __attribute__((address_space(1))) u32*)g,
                                     (__attribute__((address_space(3))) u32*)l, 16, 0, 0);
}

// ---------------- init kernels (run every call; graph-capture safe) ----------------

// Legendre fp64 recurrence -> TWO layouts, bf16 hi/lo pairs, k-extent padded to 184 w/ zeros:
//   Pa[m][l][klat]  (analysis A: contract over klat, k-contiguous)
//   Ps[m][klat][l]  (synthesis A: contract over l,  k-contiguous)
__global__ __launch_bounds__(256) void init_legendre(u16* __restrict__ Pah, u16* __restrict__ Pal,
                                                     u16* __restrict__ Psh, u16* __restrict__ Psl) {
    int idx = blockIdx.x * 256 + threadIdx.x;
    if (idx >= 181 * 181) return;
    int m = idx / 181, k = idx % 181;
    // zero pads: Pa[m][l][181+k] (k<3 threads cover all l); Ps[m][k][181..183]
    if (k < 3) {
        for (int l = 0; l < 181; ++l) {
            size_t o = (size_t)m * PMSTR2 + (size_t)l * PKSTR + 181 + k;
            Pah[o] = 0; Pal[o] = 0;
        }
    }
    for (int j = 181; j < PKSTR; ++j) {
        size_t o = (size_t)m * PMSTR2 + (size_t)k * PKSTR + j;
        Psh[o] = 0; Psl[o] = 0;
    }
    double theta = M_PI * (double)k / 180.0;
    double ct = cos(theta), st = sin(theta);
    double pmm = sqrt(1.0 / (4.0 * M_PI));
    for (int j = 1; j <= m; ++j) pmm *= -sqrt((2.0 * j + 1.0) / (2.0 * j)) * st;
    u16 h, lo;
    auto emit = [&](int l, double v) {
        split_f((float)v, h, lo);
        size_t oa = (size_t)m * PMSTR2 + (size_t)l * PKSTR + k;
        size_t os = (size_t)m * PMSTR2 + (size_t)k * PKSTR + l;
        Pah[oa] = h; Pal[oa] = lo;
        Psh[os] = h; Psl[os] = lo;
    };
    for (int l2 = 0; l2 < m; ++l2) emit(l2, 0.0);
    emit(m, pmm);
    if (m + 1 < 181) {
        double pl1 = sqrt(2.0 * m + 3.0) * ct * pmm;
        emit(m + 1, pl1);
        double pl2 = pmm;
        for (int ll = m + 2; ll < 181; ++ll) {
            double L = ll, M2 = m;
            double a = sqrt((4.0 * L * L - 1.0) / (L * L - M2 * M2));
            double b = sqrt(((2.0 * L + 1.0) * (L - 1.0 + M2) * (L - 1.0 - M2)) /
                            ((2.0 * L - 3.0) * (L * L - M2 * M2)));
            double p = a * ct * pl1 - b * pl2;
            emit(ll, p);
            pl2 = pl1; pl1 = p;
        }
    }
}

// E[m][n] (cos; +PIX: -sin) unchanged; DtT[n][m'] transposed iDFT matrix, m'-stride 384
// zero-padded (m' in [362,384)); wqs; 16B zero page.
__global__ __launch_bounds__(256) void init_trig(u16* __restrict__ Eh, u16* __restrict__ El,
                                                 u16* __restrict__ DtTh, u16* __restrict__ DtTl,
                                                 float* __restrict__ wqs, u16* __restrict__ zpb) {
    int idx = blockIdx.x * 256 + threadIdx.x;
    if (idx < 8) zpb[idx] = 0;
    if (idx < 181) {
        double theta = M_PI * (double)idx / 180.0;
        wqs[idx] = (float)(2.0 * M_PI * (M_PI / 180.0) * sin(theta) / 360.0);
    }
    if (idx >= 181 * 360) return;
    int m = idx / 360, n = idx % 360;
    int a = (m * n) % 360;           // exact angle reduction
    double ang = M_PI * (double)a / 180.0;
    double c = cos(ang), s = sin(ang);
    u16 h, l;
    split_f((float)c, h, l);        Eh[idx] = h;        El[idx] = l;
    split_f((float)(-s), h, l);     Eh[PIXg + idx] = h; El[PIXg + idx] = l;
    double cm = (m == 0 || m == 180) ? 1.0 : 2.0;
    split_f((float)(cm * c), h, l);
    DtTh[(size_t)n * 384 + m] = h;        DtTl[(size_t)n * 384 + m] = l;
    split_f((float)(-cm * s), h, l);
    DtTh[(size_t)n * 384 + 181 + m] = h;  DtTl[(size_t)n * 384 + 181 + m] = l;
    if (m == 0) {
        for (int j = 362; j < 384; ++j) { DtTh[(size_t)n * 384 + j] = 0; DtTl[(size_t)n * 384 + j] = 0; }
    }
}

// wt[l][i][o] = W[o][i][l], bf16 pair (o-contiguous writes; dhconv consumes via R-path)
__global__ __launch_bounds__(256) void transpose_wspec(const float* __restrict__ W,
                                                       u16* __restrict__ WTh, u16* __restrict__ WTl) {
    __shared__ float tile[32][33];
    int l0 = blockIdx.x * 32, o0 = blockIdx.y * 32, i = blockIdx.z;
    int c = threadIdx.x & 31, r = threadIdx.x >> 5;
#pragma unroll
    for (int j = 0; j < 4; j++) {
        int row = r + j * 8;
        float v = 0.f;
        if (l0 + c < 181) v = W[(size_t)(o0 + row) * 46336 + i * 181 + (l0 + c)];
        tile[row][c] = v;
    }
    __syncthreads();
#pragma unroll
    for (int j = 0; j < 4; j++) {
        int row = r + j * 8;
        if (l0 + row < 181) {
            u16 h, l; split_f(tile[c][row], h, l);
            size_t o = (size_t)(l0 + row) * 65536 + i * 256 + (o0 + c);
            WTh[o] = h; WTl[o] = l;
        }
    }
}

// generic fp32 -> bf16-pair splitter (weights)
__global__ __launch_bounds__(256) void split_bf16(const float* __restrict__ in,
                                                  u16* __restrict__ h, u16* __restrict__ l, int n) {
    int i = blockIdx.x * 256 + threadIdx.x;
    if (i >= n) return;
    u16 hh, ll; split_f(in[i], hh, ll);
    h[i] = hh; l[i] = ll;
}

// LayerNorm over channels (256) per pixel; emits optional fp32 [c][p] + TRANSPOSED pair [p][c]
__global__ __launch_bounds__(256) void ln_kernel(const float* __restrict__ X, float* __restrict__ Y,
                                                 u16* __restrict__ YTh, u16* __restrict__ YTl) {
    int p0 = blockIdx.x * 64;
    int t = threadIdx.x;
    int ps = t & 63, cg = t >> 6;
    int p = p0 + ps;
    bool ok = p < PIXg;
    float sum = 0.f, sumsq = 0.f;
    if (ok) {
        for (int c = cg; c < EMBg; c += 4) {
            float v = X[(size_t)c * PIXg + p];
            sum += v; sumsq += v * v;
        }
    }
    __shared__ float s1[4][64];
    __shared__ float s2[4][64];
    s1[cg][ps] = sum; s2[cg][ps] = sumsq;
    __syncthreads();
    float tot  = s1[0][ps] + s1[1][ps] + s1[2][ps] + s1[3][ps];
    float tot2 = s2[0][ps] + s2[1][ps] + s2[2][ps] + s2[3][ps];
    float mu = tot * (1.0f / 256.0f);
    float var = tot2 * (1.0f / 256.0f) - mu * mu;
    float inv = rsqrtf(var + 1e-6f);
    if (ok) {
        for (int c = cg; c < EMBg; c += 4) {
            size_t offp = (size_t)c * PIXg + p;
            float v = (X[offp] - mu) * inv;
            if (Y) Y[offp] = v;
            u16 h, l; split_f(v, h, l);
            size_t ot = (size_t)p * 256 + c;
            YTh[ot] = h; YTl[ot] = l;
        }
    }
}

// x1 = gelu(X + bias[c]) in place, float4 over [256][PIX]
__global__ __launch_bounds__(256) void gelu_bias(float* __restrict__ X, const float* __restrict__ b) {
    int idx = blockIdx.x * 256 + threadIdx.x;   // float4 index
    int c = idx / 16290;                        // PIX/4
    float bv = b[c];
    float4 v = reinterpret_cast<float4*>(X)[idx];
    v.x = gelu_f(v.x + bv); v.y = gelu_f(v.y + bv);
    v.z = gelu_f(v.z + bv); v.w = gelu_f(v.w + bv);
    reinterpret_cast<float4*>(X)[idx] = v;
}

// ---------------- fp32 strided batched GEMM (tiny-K encoder/decoder only) --------------
__global__ __launch_bounds__(256, 2) void gemm_f32(
    const float* __restrict__ A, int Ars, int Acs, int Azs, int Aps,
    const float* __restrict__ B, int Brs, int Bcs, int Bzs, int Bps,
    float* __restrict__ C, int Crs, int Ccs, int Czs, int Cps,
    const float* __restrict__ bias, const float* __restrict__ zscale,
    const float* __restrict__ resid,
    int M, int N, int K, int Zin, int flags)
{
    int z = blockIdx.z;
    if (z >= Zin) { z -= Zin; A += Aps; B += Bps; C += Cps; if (resid) resid += Cps; }
    A += (size_t)z * Azs; B += (size_t)z * Bzs; C += (size_t)z * Czs;
    if (resid) resid += (size_t)z * Czs;

    const int bm = blockIdx.y * 128, bn = blockIdx.x * 128;
    const int t = threadIdx.x;
    const int tx = t & 15, ty = t >> 4;

    __shared__ float As[16][132];
    __shared__ float Bs[16][132];

    float acc[8][8];
#pragma unroll
    for (int i = 0; i < 8; i++)
#pragma unroll
        for (int j = 0; j < 8; j++) acc[i][j] = 0.0f;

    for (int k0 = 0; k0 < K; k0 += 16) {
        if (Acs == 1) {
            int kk = t & 15, r = t >> 4;
            int gk = k0 + kk; bool kv = gk < K;
#pragma unroll
            for (int i = 0; i < 8; i++) {
                int gr = bm + r + i * 16; if (gr > M - 1) gr = M - 1;
                As[kk][r + i * 16] = kv ? A[(size_t)gr * Ars + gk] : 0.f;
            }
        } else {
            int row = t & 127, kb = t >> 7;
            int gr = bm + row; if (gr > M - 1) gr = M - 1;
            size_t base = (size_t)gr * Ars;
#pragma unroll
            for (int i = 0; i < 8; i++) {
                int gk = k0 + kb + i * 2;
                As[kb + i * 2][row] = (gk < K) ? A[base + (size_t)gk * Acs] : 0.f;
            }
        }
        if (Bcs == 1) {
            int col = t & 127, kb = t >> 7;
            int gc = bn + col; if (gc > N - 1) gc = N - 1;
#pragma unroll
            for (int i = 0; i < 8; i++) {
                int gk = k0 + kb + i * 2;
                Bs[kb + i * 2][col] = (gk < K) ? B[(size_t)gk * Brs + gc] : 0.f;
            }
        } else {
            int kk = t & 15, cb = t >> 4;
            int gk = k0 + kk; bool kv = gk < K;
#pragma unroll
            for (int i = 0; i < 8; i++) {
                int gc = bn + cb + i * 16; if (gc > N - 1) gc = N - 1;
                Bs[kk][cb + i * 16] = kv ? B[(size_t)gk * Brs + (size_t)gc * Bcs] : 0.f;
            }
        }
        __syncthreads();
#pragma unroll
        for (int kk = 0; kk < 16; kk++) {
            float4 a0 = *(const float4*)&As[kk][ty * 4];
            float4 a1 = *(const float4*)&As[kk][ty * 4 + 64];
            float4 b0 = *(const float4*)&Bs[kk][tx * 4];
            float4 b1 = *(const float4*)&Bs[kk][tx * 4 + 64];
            float av[8] = {a0.x, a0.y, a0.z, a0.w, a1.x, a1.y, a1.z, a1.w};
            float bv[8] = {b0.x, b0.y, b0.z, b0.w, b1.x, b1.y, b1.z, b1.w};
#pragma unroll
            for (int i = 0; i < 8; i++)
#pragma unroll
                for (int j = 0; j < 8; j++)
                    acc[i][j] = fmaf(av[i], bv[j], acc[i][j]);
        }
        __syncthreads();
    }

    const float zs = zscale ? zscale[z] : 1.0f;
    const bool fastN = (Ccs == 1) && (bn + 128 <= N);
#pragma unroll
    for (int i = 0; i < 8; i++) {
        int gi = bm + ty * 4 + (i & 3) + ((i >> 2) << 6);
        if (gi >= M) continue;
        float bval = bias ? bias[gi] : 0.0f;
        size_t crow = (size_t)gi * (size_t)Crs;
        if (fastN) {
#pragma unroll
            for (int h = 0; h < 2; h++) {
                int gj = bn + tx * 4 + h * 64;
                size_t off = crow + (size_t)gj;
                float4 v;
                v.x = acc[i][h * 4 + 0] * zs + bval;
                v.y = acc[i][h * 4 + 1] * zs + bval;
                v.z = acc[i][h * 4 + 2] * zs + bval;
                v.w = acc[i][h * 4 + 3] * zs + bval;
                if (resid) { float4 r = *(const float4*)&resid[off];
                             v.x += r.x; v.y += r.y; v.z += r.z; v.w += r.w; }
                if (flags & FLAG_GELU) { v.x = gelu_f(v.x); v.y = gelu_f(v.y);
                                         v.z = gelu_f(v.z); v.w = gelu_f(v.w); }
                if (flags & FLAG_ACC)  { float4 c0 = *(const float4*)&C[off];
                                         v.x += c0.x; v.y += c0.y; v.z += c0.z; v.w += c0.w; }
                *(float4*)&C[off] = v;
            }
        } else {
#pragma unroll
            for (int j = 0; j < 8; j++) {
                int gj = bn + tx * 4 + (j & 3) + ((j >> 2) << 6);
                if (gj >= N) continue;
                size_t off = crow + (size_t)gj * (size_t)Ccs;
                float v = acc[i][j] * zs + bval;
                if (resid) v += resid[off];
                if (flags & FLAG_GELU) v = gelu_f(v);
                if (flags & FLAG_ACC) v += C[off];
                C[off] = v;
            }
        }
    }
}

// ---------------- bf16x2-split MFMA GEMM (fp32-grade via 3 MFMA terms) ----------------
// C = (Ah+Al)(Bh+Bl) ~= Ah*Bh + Ah*Bl + Al*Bh, fp32 accumulate in matrix cores.
// Staging: G (k-contiguous) via global_load_lds into linear [128][32] with chunk-XOR
// x(row)=(row>>1)&3 applied on the per-lane GLOBAL source (stays within the row's 64B
// line -> coalescing preserved) and on the fragment read => 2-way (free) ds_read_b128.
// R (k-strided) via register gather + ds_write into [128][40] XOR-swizzled layout.
// HISTORY (do not regress):
//  - r1: launch_bounds(256,2) pinned VGPR=128 -> acc spill, 928MB scratch/dispatch.
//  - r2: sched_barrier(0) between MFMA clusters -> intermittent silent corruption. NO
//    scheduling intrinsics in this kernel, ever. (Source-level pass ordering is fine.)
//  - r3/r4: register staging serialized loads (compiler sinks loads to ds_write uses).
//  - r5: glds fixed staging, but VGPR=176 -> 2 waves/SIMD, Occupancy 11.6% (~1 block/CU
//    resident): latency-bound with nothing to overlap. m97 evidence: this structure needs
//    3 blocks/CU. THIS round: launch_bounds(256,3) caps VGPR at 170 (6-reg squeeze), and
//    3-pass source-ordered frag loads drop peak frag pressure 64->48 to give slack.
//    WATCH: if FETCH_SIZE balloons, the cap caused scratch -> revert to (256,1).
__global__ __launch_bounds__(256, 3) void gemm_bf16(
    const u16* __restrict__ Ah, const u16* __restrict__ Al,
    int Ars, int Acs, int Azs, int Aps,
    const u16* __restrict__ Bh, const u16* __restrict__ Bl,
    int Brs, int Bcs, int Bzs, int Bps,
    float* __restrict__ C, u16* __restrict__ Ch, u16* __restrict__ Cl,
    int Crs, int Ccs, int Czs, int Cps,
    const float* __restrict__ bias, const float* __restrict__ biasN,
    const float* __restrict__ zscale, const float* __restrict__ resid,
    const u16* __restrict__ zp,
    int M, int N, int K, int Zin, int flags)
{
    int z = blockIdx.z;
    if (z >= Zin) {
        z -= Zin;
        Ah += Aps; Al += Aps; Bh += Bps; Bl += Bps;
        if (C) C += Cps;
        if (Ch) Ch += Cps;
        if (Cl) Cl += Cps;
        if (resid) resid += Cps;
    }
    Ah += (size_t)z * Azs; Al += (size_t)z * Azs;
    Bh += (size_t)z * Bzs; Bl += (size_t)z * Bzs;
    const size_t czoff = (size_t)z * Czs;

    const int t = threadIdx.x;
    const int lane = t & 63;
    const int w = t >> 6;
    const int bm = blockIdx.y * 128, bn = blockIdx.x * 128;

    __shared__ u16 Ahs[128 * 40];
    __shared__ u16 Als[128 * 40];
    __shared__ u16 Bhs[128 * 40];
    __shared__ u16 Bls[128 * 40];

    f32x4 acc[4][4];
#pragma unroll
    for (int i = 0; i < 4; i++)
#pragma unroll
        for (int j = 0; j < 4; j++) acc[i][j] = (f32x4){0.f, 0.f, 0.f, 0.f};

    const int wm = (w >> 1) * 64, wn = (w & 1) * 64;
    const int fr = lane & 15, fgb = lane >> 4;
    const bool ag = (Acs == 1), bg = (Brs == 1);
    const int K8 = (K + 7) & ~7;
    const int rloc = lane >> 2, csl = lane & 3;   // glds: 4 lanes per 64B row, 16B chunks

    // fragment offsets (u16 index), layout per method
    int aoff[4], boff[4];
#pragma unroll
    for (int f = 0; f < 4; f++) {
        int ra = wm + f * 16 + fr;
        aoff[f] = ag ? (ra * 32 + ((fgb ^ ((ra >> 1) & 3)) << 3))
                     : (ra * 40 + (((fgb ^ (ra >> 3)) & 3) << 3));
        int rb = wn + f * 16 + fr;
        boff[f] = bg ? (rb * 32 + ((fgb ^ ((rb >> 1) & 3)) << 3))
                     : (rb * 40 + (((fgb ^ (rb >> 3)) & 3) << 3));
    }

    for (int k0 = 0; k0 < K; k0 += 32) {
        // ---- stage A ----
        if (ag) {
#pragma unroll
            for (int inst = 0; inst < 2; ++inst) {
                int r = w * 32 + inst * 16 + rloc;
                int gr = bm + r; if (gr > M - 1) gr = M - 1;
                int gk = k0 + 8 * (csl ^ ((r >> 1) & 3));
                const u16* sh = zp; const u16* sl = zp;
                if (gk < K8) { size_t o = (size_t)gr * Ars + gk; sh = Ah + o; sl = Al + o; }
                glds16(sh, &Ahs[(w * 32 + inst * 16) * 32]);
                glds16(sl, &Als[(w * 32 + inst * 16) * 32]);
            }
        } else {  // R: Ars==1
            int ml = (t & 63) * 2;
            int kg = t >> 6;
            int gr0 = bm + ml;     if (gr0 > M - 1) gr0 = M - 1;
            int gr1 = bm + ml + 1; if (gr1 > M - 1) gr1 = M - 1;
            bool pair = (gr1 == gr0 + 1);
            u32 vah[8], val8[8];
#pragma unroll
            for (int i = 0; i < 8; i++) {
                int kk = kg + 4 * i;
                int gk = k0 + kk;
                u32 vh = 0, vl = 0;
                if (gk < K) {
                    size_t o = (size_t)gk * Acs + gr0;
                    if (pair) { vh = *(const u32*)(Ah + o); vl = *(const u32*)(Al + o); }
                    else {
                        vh = Ah[o]; vl = Al[o];
                        u32 h1 = Ah[(size_t)gk * Acs + gr1], l1 = Al[(size_t)gk * Acs + gr1];
                        vh |= h1 << 16; vl |= l1 << 16;
                    }
                }
                vah[i] = vh; val8[i] = vl;
            }
#pragma unroll
            for (int i = 0; i < 8; i++) {
                int kk = kg + 4 * i;
                int blk = (kk >> 3) & 3;
                int s0 = ml * 40 + (((blk ^ (ml >> 3)) & 3) << 3) + (kk & 7);
                int s1 = (ml + 1) * 40 + (((blk ^ ((ml + 1) >> 3)) & 3) << 3) + (kk & 7);
                Ahs[s0] = (u16)vah[i]; Ahs[s1] = (u16)(vah[i] >> 16);
                Als[s0] = (u16)val8[i]; Als[s1] = (u16)(val8[i] >> 16);
            }
        }
        // ---- stage B ----
        if (bg) {
#pragma unroll
            for (int inst = 0; inst < 2; ++inst) {
                int cidx = w * 32 + inst * 16 + rloc;
                int gj = bn + cidx; if (gj > N - 1) gj = N - 1;
                int gk = k0 + 8 * (csl ^ ((cidx >> 1) & 3));
                const u16* sh = zp; const u16* sl = zp;
                if (gk < K8) { size_t o = (size_t)gj * Bcs + gk; sh = Bh + o; sl = Bl + o; }
                glds16(sh, &Bhs[(w * 32 + inst * 16) * 32]);
                glds16(sl, &Bls[(w * 32 + inst * 16) * 32]);
            }
        } else {  // R: Bcs==1
            int jl = (t & 63) * 2;
            int kg = t >> 6;
            int gj0 = bn + jl;     if (gj0 > N - 1) gj0 = N - 1;
            int gj1 = bn + jl + 1; if (gj1 > N - 1) gj1 = N - 1;
            bool pair = (gj1 == gj0 + 1);
            u32 vbh[8], vbl[8];
#pragma unroll
            for (int i = 0; i < 8; i++) {
                int kk = kg + 4 * i;
                int gk = k0 + kk;
                u32 vh = 0, vl = 0;
                if (gk < K) {
                    size_t o = (size_t)gk * Brs + gj0;
                    if (pair) { vh = *(const u32*)(Bh + o); vl = *(const u32*)(Bl + o); }
                    else {
                        vh = Bh[o]; vl = Bl[o];
                        u32 h1 = Bh[(size_t)gk * Brs + gj1], l1 = Bl[(size_t)gk * Brs + gj1];
                        vh |= h1 << 16; vl |= l1 << 16;
                    }
                }
                vbh[i] = vh; vbl[i] = vl;
            }
#pragma unroll
            for (int i = 0; i < 8; i++) {
                int kk = kg + 4 * i;
                int blk = (kk >> 3) & 3;
                int s0 = jl * 40 + (((blk ^ (jl >> 3)) & 3) << 3) + (kk & 7);
                int s1 = (jl + 1) * 40 + (((blk ^ ((jl + 1) >> 3)) & 3) << 3) + (kk & 7);
                Bhs[s0] = (u16)vbh[i]; Bhs[s1] = (u16)(vbh[i] >> 16);
                Bls[s0] = (u16)vbl[i]; Bls[s1] = (u16)(vbl[i] >> 16);
            }
        }
        __syncthreads();   // compiler emits vmcnt(0)+lgkmcnt(0) here: glds + ds_writes land

        // 3 source-level passes (NO scheduling intrinsics): peak frag live 48 VGPR not 64.
        {
            bf16x8 fah[4], fbh[4];
#pragma unroll
            for (int f = 0; f < 4; f++) {
                fah[f] = *(const bf16x8*)(Ahs + aoff[f]);
                fbh[f] = *(const bf16x8*)(Bhs + boff[f]);
            }
#pragma unroll
            for (int i = 0; i < 4; i++)
#pragma unroll
                for (int j = 0; j < 4; j++)
                    acc[i][j] = __builtin_amdgcn_mfma_f32_16x16x32_bf16(fah[i], fbh[j], acc[i][j], 0, 0, 0);
            bf16x8 fbl[4];
#pragma unroll
            for (int f = 0; f < 4; f++) fbl[f] = *(const bf16x8*)(Bls + boff[f]);
#pragma unroll
            for (int i = 0; i < 4; i++)
#pragma unroll
                for (int j = 0; j < 4; j++)
                    acc[i][j] = __builtin_amdgcn_mfma_f32_16x16x32_bf16(fah[i], fbl[j], acc[i][j], 0, 0, 0);
            bf16x8 fal[4];
#pragma unroll
            for (int f = 0; f < 4; f++) fal[f] = *(const bf16x8*)(Als + aoff[f]);
#pragma unroll
            for (int i = 0; i < 4; i++)
#pragma unroll
                for (int j = 0; j < 4; j++)
                    acc[i][j] = __builtin_amdgcn_mfma_f32_16x16x32_bf16(fal[i], fbh[j], acc[i][j], 0, 0, 0);
        }
        __syncthreads();
    }

    const float zs = zscale ? zscale[z] : 1.0f;
#pragma unroll
    for (int i = 0; i < 4; i++) {
#pragma unroll
        for (int r = 0; r < 4; r++) {
            int grow = bm + wm + i * 16 + (lane >> 4) * 4 + r;   // D row = (lane>>4)*4+reg
            if (grow >= M) continue;
            float bval = bias ? bias[grow] : 0.0f;
            size_t rowoff = czoff + (size_t)grow * Crs;
#pragma unroll
            for (int j = 0; j < 4; j++) {
                int gcol = bn + wn + j * 16 + fr;                 // D col = lane&15
                if (gcol >= N) continue;
                size_t off = rowoff + (size_t)gcol * Ccs;
                float v = acc[i][j][r] * zs + bval;
                if (biasN) v += biasN[gcol];
                if (resid) v += resid[off];
                if (flags & FLAG_ACC) v += C[off];
                if (flags & FLAG_GELU) v = gelu_f(v);
                if (flags & FLAG_F32) C[off] = v;
                if (flags & FLAG_BF16) {
                    u16 h, l; split_f(v, h, l);
                    Ch[off] = h; Cl[off] = l;
                }
            }
        }
    }
}

static inline void launch_gemm(hipStream_t s,
    const float* A, int Ars, int Acs, int Azs, int Aps,
    const float* B, int Brs, int Bcs, int Bzs, int Bps,
    float* C, int Crs, int Ccs, int Czs, int Cps,
    const float* bias, const float* zscale, const float* resid,
    int M, int N, int K, int Zin, int nplanes, int flags)
{
    dim3 grid((N + 127) / 128, (M + 127) / 128, Zin * nplanes);
    hipLaunchKernelGGL(gemm_f32, grid, dim3(256), 0, s,
                       A, Ars, Acs, Azs, Aps, B, Brs, Bcs, Bzs, Bps,
                       C, Crs, Ccs, Czs, Cps, bias, zscale, resid,
                       M, N, K, Zin, flags);
}

static inline void launch_gemm16(hipStream_t s,
    const u16* Ah, const u16* Al, int Ars, int Acs, int Azs, int Aps,
    const u16* Bh, const u16* Bl, int Brs, int Bcs, int Bzs, int Bps,
    float* C, u16* Ch, u16* Cl, int Crs, int Ccs, int Czs, int Cps,
    const float* bias, const float* biasN, const float* zscale, const float* resid,
    const u16* zp, int M, int N, int K, int Zin, int nplanes, int flags)
{
    dim3 grid((N + 127) / 128, (M + 127) / 128, Zin * nplanes);
    hipLaunchKernelGGL(gemm_bf16, grid, dim3(256), 0, s,
                       Ah, Al, Ars, Acs, Azs, Aps, Bh, Bl, Brs, Bcs, Bzs, Bps,
                       C, Ch, Cl, Crs, Ccs, Czs, Cps, bias, biasN, zscale, resid, zp,
                       M, N, K, Zin, flags);
}

extern "C" void kernel_launch(void* const* d_in, const int* in_sizes, int n_in,
                              void* d_out, int out_size, void* d_ws, size_t ws_size,
                              hipStream_t stream)
{
    const float* x      = (const float*)d_in[0];
    const float* w_enc  = (const float*)d_in[1];
    const float* b_enc  = (const float*)d_in[2];
    const float* pos    = (const float*)d_in[3];
    const float* w_spec = (const float*)d_in[4];
    const float* b_spec = (const float*)d_in[5];
    const float* w_is   = (const float*)d_in[6];
    const float* b_is   = (const float*)d_in[7];
    const float* w_f1   = (const float*)d_in[8];
    const float* b_f1   = (const float*)d_in[9];
    const float* w_f2   = (const float*)d_in[10];
    const float* b_f2   = (const float*)d_in[11];
    const float* w_dec  = (const float*)d_in[12];
    const float* b_dec  = (const float*)d_in[13];
    float* out = (float*)d_out;

    // ---- workspace layout (bytes); total ~451 MB ----
    char* base = (char*)d_ws;
    size_t off = 0;
    auto alloc = [&](size_t bytes) { size_t o = off; off += (bytes + 255) & ~(size_t)255; return o; };
    u16* Pah = (u16*)(base + alloc(12056048));   // 181*33304 u16
    u16* Pal = (u16*)(base + alloc(12056048));
    u16* Psh = (u16*)(base + alloc(12056048));
    u16* Psl = (u16*)(base + alloc(12056048));
    u16* Eh  = (u16*)(base + alloc(260640));     // 2*PIX u16
    u16* El  = (u16*)(base + alloc(260640));
    u16* DtTh = (u16*)(base + alloc(276480));    // 360*384 u16
    u16* DtTl = (u16*)(base + alloc(276480));
    float* wqs = (float*)(base + alloc(724));
    u16* zp  = (u16*)(base + alloc(256));        // 16B zero page (k-tail source)
    // spectral bf16 pair bufs, ONE contiguous block (hmlpT overlay needs contiguity)
    u16* SP  = (u16*)(base + alloc(134189056));  // 4 * PLANE-pair u16 regions
    u16* S0h = SP;
    u16* S0l = SP + 16773632;
    u16* S1h = SP + 2 * 16773632;
    u16* S1l = SP + 3 * 16773632;
    u16* hmlpTh = SP;                    // [PIX][512] u16, spectral bufs dead by MLP time
    u16* hmlpTl = SP + 33361920;
    float* xn  = (float*)(base + alloc(66723840));   // fp32 [c][p] (fc2 residual)
    u16* xnTh = (u16*)(base + alloc(33361920));      // transposed pair [p][c]
    u16* xnTl = (u16*)(base + alloc(33361920));
    float* hbuf = (float*)(base + alloc(66723840));
    float* tA   = (float*)(base + alloc(66723840));
    u16* wth = (u16*)tA;                 // wt pair overlays tA; dead once iDFT writes tA
    u16* wtl = wth + 11862016;           // 181*65536
    u16* wish = (u16*)(base + alloc(131072));
    u16* wisl = (u16*)(base + alloc(131072));
    u16* wf1h = (u16*)(base + alloc(262144));
    u16* wf1l = (u16*)(base + alloc(262144));
    u16* wf2h = (u16*)(base + alloc(262144));
    u16* wf2l = (u16*)(base + alloc(262144));

    init_legendre<<<(181 * 181 + 255) / 256, 256, 0, stream>>>(Pah, Pal, Psh, Psl);
    init_trig<<<(181 * 360 + 255) / 256, 256, 0, stream>>>(Eh, El, DtTh, DtTl, wqs, zp);

    // encoder: h = w_enc*x + b_enc + pos_emb  (K=26, memory-bound: keep fp32 GEMM)
    launch_gemm(stream, w_enc, 26, 1, 0, 0,  x, PIXg, 1, 0, 0,  hbuf, PIXg, 1, 0, 0,
                b_enc, nullptr, pos, EMBg, PIXg, 26, 1, 1, 0);

    for (int L = 0; L < 4; ++L) {
        const float* wsp = w_spec + (size_t)L * EMBg * EMBg * 181;
        const float* bsp = b_spec + (size_t)L * EMBg;
        const float* wis = w_is   + (size_t)L * EMBg * EMBg;
        const float* bis = b_is   + (size_t)L * EMBg;
        const float* wf1 = w_f1   + (size_t)L * MHIDg * EMBg;
        const float* bf1 = b_f1   + (size_t)L * MHIDg;
        const float* wf2 = w_f2   + (size_t)L * EMBg * MHIDg;
        const float* bf2 = b_f2   + (size_t)L * EMBg;

        transpose_wspec<<<dim3(6, 8, 256), 256, 0, stream>>>(wsp, wth, wtl);
        split_bf16<<<(65536 + 255) / 256, 256, 0, stream>>>(wis, wish, wisl, 65536);
        split_bf16<<<(131072 + 255) / 256, 256, 0, stream>>>(wf1, wf1h, wf1l, 131072);
        split_bf16<<<(131072 + 255) / 256, 256, 0, stream>>>(wf2, wf2h, wf2l, 131072);

        // xn = LN(h): fp32 [c][p] + transposed pair [p][c]
        ln_kernel<<<1019, 256, 0, stream>>>(hbuf, xn, xnTh, xnTl);

        // DFT (z=lat k, planes cos/sin): S0[m][k][c] = (sum_n E[m][n]*xnT[k*360+n][c])*wqs[k]
        // A=E: G (k=n contig). B=xnT: R (panel contiguous).
        launch_gemm16(stream, Eh, El, 360, 1, 0, PIXg,  xnTh, xnTl, 256, 1, 92160, 0,
                      nullptr, S0h, S0l, 46336, 1, 256, PLANEg,
                      nullptr, nullptr, wqs, nullptr, zp, 181, 256, 360, 181, 2, FLAG_BF16);
        // analysis (z=m): S1[l][m][c] = sum_k Pa[m][l][k]*S0[m][k][c]
        // A=Pa: G. B=S0: R (contiguous 92KB panel per z).
        launch_gemm16(stream, Pah, Pal, PKSTR, 1, PMSTR2, 0,  S0h, S0l, 256, 1, 46336, PLANEg,
                      nullptr, S1h, S1l, 46336, 1, 256, PLANEg,
                      nullptr, nullptr, nullptr, nullptr, zp, 181, 256, 181, 181, 2, FLAG_BF16);
        // dhconv (z=l): S0'[m][l][o] = sum_i S1[l][m][i]*wt[l][i][o]
        // A=S1: G (k=i contig). B=wt: R (contiguous 128KB panel per z).
        launch_gemm16(stream, S1h, S1l, 256, 1, 46336, PLANEg,  wth, wtl, 256, 1, 65536, 0,
                      nullptr, S0h, S0l, 46336, 1, 256, PLANEg,
                      nullptr, nullptr, nullptr, nullptr, zp, 181, 256, 256, 181, 2, FLAG_BF16);
        // synthesis (z=m): S1'[k][pl*181+m][c] = sum_l Ps[m][k][l]*S0'[m][l][c]
        // A=Ps: G. B=S0': R (contiguous panel).
        launch_gemm16(stream, Psh, Psl, PKSTR, 1, PMSTR2, 0,  S0h, S0l, 256, 1, 46336, PLANEg,
                      nullptr, S1h, S1l, 92672, 1, 256, 46336,
                      nullptr, nullptr, nullptr, nullptr, zp, 181, 256, 181, 181, 2, FLAG_BF16);
        // iDFT (z=lat k): tA[c][k*360+n] = sum_{m'} S1'[k][m'][c]*DtT[n][m']
        // A=S1': R (contiguous 185KB panel per z). B=DtT: G (k=m' contig, 384-padded).
        launch_gemm16(stream, S1h, S1l, 1, 256, 92672, 0,  DtTh, DtTl, 1, 384, 0, 0,
                      tA, nullptr, nullptr, PIXg, 1, 360, 0,
                      nullptr, nullptr, nullptr, nullptr, zp, 256, 360, 362, 181, 1, FLAG_F32);
        // inner skip into tA: tA += wis*xn + bis   (A: G; B=xnT: G)
        launch_gemm16(stream, wish, wisl, 256, 1, 0, 0,  xnTh, xnTl, 1, 256, 0, 0,
                      tA, nullptr, nullptr, PIXg, 1, 0, 0,
                      bis, nullptr, nullptr, nullptr, zp, 256, PIXg, 256, 1, 1, FLAG_F32 | FLAG_ACC);
        // x1 = gelu(tA + b_spec) in place
        gelu_bias<<<16290, 256, 0, stream>>>(tA, bsp);
        // x2 = LN(x1): transposed pair only (fc1 consumes [p][c]); xn fp32 preserved
        ln_kernel<<<1019, 256, 0, stream>>>(tA, nullptr, xnTh, xnTl);
        // fc1 TRANSPOSED: hmlpT[p][h] = gelu(sum_i xnT[p][i]*wf1[h][i] + bf1[h])
        // M=PIX rows p, N=512 cols h, col-bias bf1. A=xnT: G; B=wf1: G.
        launch_gemm16(stream, xnTh, xnTl, 256, 1, 0, 0,  wf1h, wf1l, 1, 256, 0, 0,
                      nullptr, hmlpTh, hmlpTl, 512, 1, 0, 0,
                      nullptr, bf1, nullptr, nullptr, zp, PIXg, 512, 256, 1, 1, FLAG_BF16 | FLAG_GELU);
        // fc2 + residual xn -> h: hbuf[c][p] = sum_h wf2[c][h]*hmlpT[p][h] + bf2 + xn
        // A=wf2: G; B=hmlpT: G.
        launch_gemm16(stream, wf2h, wf2l, 512, 1, 0, 0,  hmlpTh, hmlpTl, 1, 512, 0, 0,
                      hbuf, nullptr, nullptr, PIXg, 1, 0, 0,
                      bf2, nullptr, nullptr, xn, zp, EMBg, PIXg, 512, 1, 1, FLAG_F32);
    }

    // decoder: out = w_dec[:, :256]*h + w_dec[:, 256:]*x + b_dec  (tiny M: fp32 GEMM)
    launch_gemm(stream, w_dec, 282, 1, 0, 0,  hbuf, PIXg, 1, 0, 0,  out, PIXg, 1, 0, 0,
                b_dec, nullptr, nullptr, 26, PIXg, 256, 1, 1, 0);
    launch_gemm(stream, w_dec + 256, 282, 1, 0, 0,  x, PIXg, 1, 0, 0,  out, PIXg, 1, 0, 0,
                nullptr, nullptr, nullptr, 26, PIXg, 26, 1, 1, FLAG_ACC);
}

// Round 7
// 8685.142 us; speedup vs baseline: 2.5625x; 2.5625x over previous
//
#include <hip/hip_runtime.h>
#include <math.h>

#define NLATg 181
#define NLONg 360
#define PIXg  65160        // 181*360
#define EMBg  256
#define MHIDg 512
#define PLANEg 8386816     // 181*46336
#define PKSTR 184          // padded k-extent stride in Pa/Ps (mult of 8, zero-padded)
#define PMSTR2 33304       // 181*184, per-m stride in Pa/Ps

#define FLAG_GELU 1
#define FLAG_ACC  2
#define FLAG_F32  4
#define FLAG_BF16 8

typedef unsigned short u16;
typedef unsigned int   u32;
typedef __attribute__((ext_vector_type(8))) short bf16x8;
typedef __attribute__((ext_vector_type(4))) float f32x4;

__device__ __forceinline__ float gelu_f(float x) {
    return 0.5f * x * (1.0f + erff(x * 0.70710678118654752440f));
}

// fp32 -> (hi, lo) truncated bf16 pair: v ~= hi + lo with ~2^-16 relative error.
__device__ __forceinline__ void split_f(float v, u16& h, u16& l) {
    u32 u = __float_as_uint(v);
    h = (u16)(u >> 16);
    float hf = __uint_as_float(u & 0xFFFF0000u);
    l = (u16)(__float_as_uint(v - hf) >> 16);
}

// async global->LDS, 16B per lane; LDS dest = wave-uniform base + lane*16 (HW rule)
__device__ __forceinline__ void glds16(const u16* g, u16* l) {
    __builtin_amdgcn_global_load_lds((const __attribute__((address_space(1))) u32*)g,
                                     (__attribute__((address_space(3))) u32*)l, 16, 0, 0);
}

// ---------------- init kernels (run every call; graph-capture safe) ----------------

// Legendre fp64 recurrence -> TWO layouts, bf16 hi/lo pairs, k-extent padded to 184 w/ zeros:
//   Pa[m][l][klat]  (analysis A: contract over klat, k-contiguous)
//   Ps[m][klat][l]  (synthesis A: contract over l,  k-contiguous)
__global__ __launch_bounds__(256) void init_legendre(u16* __restrict__ Pah, u16* __restrict__ Pal,
                                                     u16* __restrict__ Psh, u16* __restrict__ Psl) {
    int idx = blockIdx.x * 256 + threadIdx.x;
    if (idx >= 181 * 181) return;
    int m = idx / 181, k = idx % 181;
    // zero pads: Pa[m][l][181+k] (k<3 threads cover all l); Ps[m][k][181..183]
    if (k < 3) {
        for (int l = 0; l < 181; ++l) {
            size_t o = (size_t)m * PMSTR2 + (size_t)l * PKSTR + 181 + k;
            Pah[o] = 0; Pal[o] = 0;
        }
    }
    for (int j = 181; j < PKSTR; ++j) {
        size_t o = (size_t)m * PMSTR2 + (size_t)k * PKSTR + j;
        Psh[o] = 0; Psl[o] = 0;
    }
    double theta = M_PI * (double)k / 180.0;
    double ct = cos(theta), st = sin(theta);
    double pmm = sqrt(1.0 / (4.0 * M_PI));
    for (int j = 1; j <= m; ++j) pmm *= -sqrt((2.0 * j + 1.0) / (2.0 * j)) * st;
    u16 h, lo;
    auto emit = [&](int l, double v) {
        split_f((float)v, h, lo);
        size_t oa = (size_t)m * PMSTR2 + (size_t)l * PKSTR + k;
        size_t os = (size_t)m * PMSTR2 + (size_t)k * PKSTR + l;
        Pah[oa] = h; Pal[oa] = lo;
        Psh[os] = h; Psl[os] = lo;
    };
    for (int l2 = 0; l2 < m; ++l2) emit(l2, 0.0);
    emit(m, pmm);
    if (m + 1 < 181) {
        double pl1 = sqrt(2.0 * m + 3.0) * ct * pmm;
        emit(m + 1, pl1);
        double pl2 = pmm;
        for (int ll = m + 2; ll < 181; ++ll) {
            double L = ll, M2 = m;
            double a = sqrt((4.0 * L * L - 1.0) / (L * L - M2 * M2));
            double b = sqrt(((2.0 * L + 1.0) * (L - 1.0 + M2) * (L - 1.0 - M2)) /
                            ((2.0 * L - 3.0) * (L * L - M2 * M2)));
            double p = a * ct * pl1 - b * pl2;
            emit(ll, p);
            pl2 = pl1; pl1 = p;
        }
    }
}

// E[m][n] (cos; +PIX: -sin) unchanged; DtT[n][m'] transposed iDFT matrix, m'-stride 384
// zero-padded (m' in [362,384)); wqs; 16B zero page.
__global__ __launch_bounds__(256) void init_trig(u16* __restrict__ Eh, u16* __restrict__ El,
                                                 u16* __restrict__ DtTh, u16* __restrict__ DtTl,
                                                 float* __restrict__ wqs, u16* __restrict__ zpb) {
    int idx = blockIdx.x * 256 + threadIdx.x;
    if (idx < 8) zpb[idx] = 0;
    if (idx < 181) {
        double theta = M_PI * (double)idx / 180.0;
        wqs[idx] = (float)(2.0 * M_PI * (M_PI / 180.0) * sin(theta) / 360.0);
    }
    if (idx >= 181 * 360) return;
    int m = idx / 360, n = idx % 360;
    int a = (m * n) % 360;           // exact angle reduction
    double ang = M_PI * (double)a / 180.0;
    double c = cos(ang), s = sin(ang);
    u16 h, l;
    split_f((float)c, h, l);        Eh[idx] = h;        El[idx] = l;
    split_f((float)(-s), h, l);     Eh[PIXg + idx] = h; El[PIXg + idx] = l;
    double cm = (m == 0 || m == 180) ? 1.0 : 2.0;
    split_f((float)(cm * c), h, l);
    DtTh[(size_t)n * 384 + m] = h;        DtTl[(size_t)n * 384 + m] = l;
    split_f((float)(-cm * s), h, l);
    DtTh[(size_t)n * 384 + 181 + m] = h;  DtTl[(size_t)n * 384 + 181 + m] = l;
    if (m == 0) {
        for (int j = 362; j < 384; ++j) { DtTh[(size_t)n * 384 + j] = 0; DtTl[(size_t)n * 384 + j] = 0; }
    }
}

// wt[l][i][o] = W[o][i][l], bf16 pair (o-contiguous writes; dhconv consumes via R-path)
__global__ __launch_bounds__(256) void transpose_wspec(const float* __restrict__ W,
                                                       u16* __restrict__ WTh, u16* __restrict__ WTl) {
    __shared__ float tile[32][33];
    int l0 = blockIdx.x * 32, o0 = blockIdx.y * 32, i = blockIdx.z;
    int c = threadIdx.x & 31, r = threadIdx.x >> 5;
#pragma unroll
    for (int j = 0; j < 4; j++) {
        int row = r + j * 8;
        float v = 0.f;
        if (l0 + c < 181) v = W[(size_t)(o0 + row) * 46336 + i * 181 + (l0 + c)];
        tile[row][c] = v;
    }
    __syncthreads();
#pragma unroll
    for (int j = 0; j < 4; j++) {
        int row = r + j * 8;
        if (l0 + row < 181) {
            u16 h, l; split_f(tile[c][row], h, l);
            size_t o = (size_t)(l0 + row) * 65536 + i * 256 + (o0 + c);
            WTh[o] = h; WTl[o] = l;
        }
    }
}

// generic fp32 -> bf16-pair splitter (weights)
__global__ __launch_bounds__(256) void split_bf16(const float* __restrict__ in,
                                                  u16* __restrict__ h, u16* __restrict__ l, int n) {
    int i = blockIdx.x * 256 + threadIdx.x;
    if (i >= n) return;
    u16 hh, ll; split_f(in[i], hh, ll);
    h[i] = hh; l[i] = ll;
}

// LayerNorm over channels (256) per pixel; emits optional fp32 [c][p] + TRANSPOSED pair [p][c]
__global__ __launch_bounds__(256) void ln_kernel(const float* __restrict__ X, float* __restrict__ Y,
                                                 u16* __restrict__ YTh, u16* __restrict__ YTl) {
    int p0 = blockIdx.x * 64;
    int t = threadIdx.x;
    int ps = t & 63, cg = t >> 6;
    int p = p0 + ps;
    bool ok = p < PIXg;
    float sum = 0.f, sumsq = 0.f;
    if (ok) {
        for (int c = cg; c < EMBg; c += 4) {
            float v = X[(size_t)c * PIXg + p];
            sum += v; sumsq += v * v;
        }
    }
    __shared__ float s1[4][64];
    __shared__ float s2[4][64];
    s1[cg][ps] = sum; s2[cg][ps] = sumsq;
    __syncthreads();
    float tot  = s1[0][ps] + s1[1][ps] + s1[2][ps] + s1[3][ps];
    float tot2 = s2[0][ps] + s2[1][ps] + s2[2][ps] + s2[3][ps];
    float mu = tot * (1.0f / 256.0f);
    float var = tot2 * (1.0f / 256.0f) - mu * mu;
    float inv = rsqrtf(var + 1e-6f);
    if (ok) {
        for (int c = cg; c < EMBg; c += 4) {
            size_t offp = (size_t)c * PIXg + p;
            float v = (X[offp] - mu) * inv;
            if (Y) Y[offp] = v;
            u16 h, l; split_f(v, h, l);
            size_t ot = (size_t)p * 256 + c;
            YTh[ot] = h; YTl[ot] = l;
        }
    }
}

// x1 = gelu(X + bias[c]) in place, float4 over [256][PIX]
__global__ __launch_bounds__(256) void gelu_bias(float* __restrict__ X, const float* __restrict__ b) {
    int idx = blockIdx.x * 256 + threadIdx.x;   // float4 index
    int c = idx / 16290;                        // PIX/4
    float bv = b[c];
    float4 v = reinterpret_cast<float4*>(X)[idx];
    v.x = gelu_f(v.x + bv); v.y = gelu_f(v.y + bv);
    v.z = gelu_f(v.z + bv); v.w = gelu_f(v.w + bv);
    reinterpret_cast<float4*>(X)[idx] = v;
}

// ---------------- fp32 strided batched GEMM (tiny-K encoder/decoder only) --------------
__global__ __launch_bounds__(256, 2) void gemm_f32(
    const float* __restrict__ A, int Ars, int Acs, int Azs, int Aps,
    const float* __restrict__ B, int Brs, int Bcs, int Bzs, int Bps,
    float* __restrict__ C, int Crs, int Ccs, int Czs, int Cps,
    const float* __restrict__ bias, const float* __restrict__ zscale,
    const float* __restrict__ resid,
    int M, int N, int K, int Zin, int flags)
{
    int z = blockIdx.z;
    if (z >= Zin) { z -= Zin; A += Aps; B += Bps; C += Cps; if (resid) resid += Cps; }
    A += (size_t)z * Azs; B += (size_t)z * Bzs; C += (size_t)z * Czs;
    if (resid) resid += (size_t)z * Czs;

    const int bm = blockIdx.y * 128, bn = blockIdx.x * 128;
    const int t = threadIdx.x;
    const int tx = t & 15, ty = t >> 4;

    __shared__ float As[16][132];
    __shared__ float Bs[16][132];

    float acc[8][8];
#pragma unroll
    for (int i = 0; i < 8; i++)
#pragma unroll
        for (int j = 0; j < 8; j++) acc[i][j] = 0.0f;

    for (int k0 = 0; k0 < K; k0 += 16) {
        if (Acs == 1) {
            int kk = t & 15, r = t >> 4;
            int gk = k0 + kk; bool kv = gk < K;
#pragma unroll
            for (int i = 0; i < 8; i++) {
                int gr = bm + r + i * 16; if (gr > M - 1) gr = M - 1;
                As[kk][r + i * 16] = kv ? A[(size_t)gr * Ars + gk] : 0.f;
            }
        } else {
            int row = t & 127, kb = t >> 7;
            int gr = bm + row; if (gr > M - 1) gr = M - 1;
            size_t base = (size_t)gr * Ars;
#pragma unroll
            for (int i = 0; i < 8; i++) {
                int gk = k0 + kb + i * 2;
                As[kb + i * 2][row] = (gk < K) ? A[base + (size_t)gk * Acs] : 0.f;
            }
        }
        if (Bcs == 1) {
            int col = t & 127, kb = t >> 7;
            int gc = bn + col; if (gc > N - 1) gc = N - 1;
#pragma unroll
            for (int i = 0; i < 8; i++) {
                int gk = k0 + kb + i * 2;
                Bs[kb + i * 2][col] = (gk < K) ? B[(size_t)gk * Brs + gc] : 0.f;
            }
        } else {
            int kk = t & 15, cb = t >> 4;
            int gk = k0 + kk; bool kv = gk < K;
#pragma unroll
            for (int i = 0; i < 8; i++) {
                int gc = bn + cb + i * 16; if (gc > N - 1) gc = N - 1;
                Bs[kk][cb + i * 16] = kv ? B[(size_t)gk * Brs + (size_t)gc * Bcs] : 0.f;
            }
        }
        __syncthreads();
#pragma unroll
        for (int kk = 0; kk < 16; kk++) {
            float4 a0 = *(const float4*)&As[kk][ty * 4];
            float4 a1 = *(const float4*)&As[kk][ty * 4 + 64];
            float4 b0 = *(const float4*)&Bs[kk][tx * 4];
            float4 b1 = *(const float4*)&Bs[kk][tx * 4 + 64];
            float av[8] = {a0.x, a0.y, a0.z, a0.w, a1.x, a1.y, a1.z, a1.w};
            float bv[8] = {b0.x, b0.y, b0.z, b0.w, b1.x, b1.y, b1.z, b1.w};
#pragma unroll
            for (int i = 0; i < 8; i++)
#pragma unroll
                for (int j = 0; j < 8; j++)
                    acc[i][j] = fmaf(av[i], bv[j], acc[i][j]);
        }
        __syncthreads();
    }

    const float zs = zscale ? zscale[z] : 1.0f;
    const bool fastN = (Ccs == 1) && (bn + 128 <= N);
#pragma unroll
    for (int i = 0; i < 8; i++) {
        int gi = bm + ty * 4 + (i & 3) + ((i >> 2) << 6);
        if (gi >= M) continue;
        float bval = bias ? bias[gi] : 0.0f;
        size_t crow = (size_t)gi * (size_t)Crs;
        if (fastN) {
#pragma unroll
            for (int h = 0; h < 2; h++) {
                int gj = bn + tx * 4 + h * 64;
                size_t off = crow + (size_t)gj;
                float4 v;
                v.x = acc[i][h * 4 + 0] * zs + bval;
                v.y = acc[i][h * 4 + 1] * zs + bval;
                v.z = acc[i][h * 4 + 2] * zs + bval;
                v.w = acc[i][h * 4 + 3] * zs + bval;
                if (resid) { float4 r = *(const float4*)&resid[off];
                             v.x += r.x; v.y += r.y; v.z += r.z; v.w += r.w; }
                if (flags & FLAG_GELU) { v.x = gelu_f(v.x); v.y = gelu_f(v.y);
                                         v.z = gelu_f(v.z); v.w = gelu_f(v.w); }
                if (flags & FLAG_ACC)  { float4 c0 = *(const float4*)&C[off];
                                         v.x += c0.x; v.y += c0.y; v.z += c0.z; v.w += c0.w; }
                *(float4*)&C[off] = v;
            }
        } else {
#pragma unroll
            for (int j = 0; j < 8; j++) {
                int gj = bn + tx * 4 + (j & 3) + ((j >> 2) << 6);
                if (gj >= N) continue;
                size_t off = crow + (size_t)gj * (size_t)Ccs;
                float v = acc[i][j] * zs + bval;
                if (resid) v += resid[off];
                if (flags & FLAG_GELU) v = gelu_f(v);
                if (flags & FLAG_ACC) v += C[off];
                C[off] = v;
            }
        }
    }
}

// ---------------- bf16x2-split MFMA GEMM (fp32-grade via 3 MFMA terms) ----------------
// C = (Ah+Al)(Bh+Bl) ~= Ah*Bh + Ah*Bl + Al*Bh, fp32 accumulate in matrix cores.
// Staging: G (k-contiguous) via global_load_lds into linear [128][32] with chunk-XOR
// x(row)=(row>>1)&3 on the per-lane GLOBAL source (stays within the row's 64B line) and
// on the fragment read => conflict-free ds_read_b128 (r6 PMC: SQ_LDS_BANK_CONFLICT = 0).
// R (k-strided) via register gather + ds_write into [128][40] XOR-swizzled layout.
// HISTORY (do not regress):
//  - r1: launch_bounds(256,2) pinned VGPR=128 -> acc spill, 928MB scratch/dispatch.
//  - r2: sched_barrier(0) between MFMA clusters -> intermittent silent corruption. NO
//    scheduling intrinsics in this kernel, ever. (Source-level pass ordering is fine.)
//  - r3/r4: register staging serialized loads (compiler sinks loads to ds_write uses).
//  - r5: glds staging, (256,1): VGPR=176, no spill, 326us top dispatch, Occ 11.6%.
//  - r6: (256,3) forced VGPR=84 -> total spill (1.1GB FETCH + 1.7GB WRITE/dispatch,
//    886us). Occupancy CANNOT be bought with launch_bounds on this body; min viable
//    VGPR ~176. Reverted to (256,1). Swizzle fix from r6 kept (conflicts 4.18M -> 0).
__global__ __launch_bounds__(256, 1) void gemm_bf16(
    const u16* __restrict__ Ah, const u16* __restrict__ Al,
    int Ars, int Acs, int Azs, int Aps,
    const u16* __restrict__ Bh, const u16* __restrict__ Bl,
    int Brs, int Bcs, int Bzs, int Bps,
    float* __restrict__ C, u16* __restrict__ Ch, u16* __restrict__ Cl,
    int Crs, int Ccs, int Czs, int Cps,
    const float* __restrict__ bias, const float* __restrict__ biasN,
    const float* __restrict__ zscale, const float* __restrict__ resid,
    const u16* __restrict__ zp,
    int M, int N, int K, int Zin, int flags)
{
    int z = blockIdx.z;
    if (z >= Zin) {
        z -= Zin;
        Ah += Aps; Al += Aps; Bh += Bps; Bl += Bps;
        if (C) C += Cps;
        if (Ch) Ch += Cps;
        if (Cl) Cl += Cps;
        if (resid) resid += Cps;
    }
    Ah += (size_t)z * Azs; Al += (size_t)z * Azs;
    Bh += (size_t)z * Bzs; Bl += (size_t)z * Bzs;
    const size_t czoff = (size_t)z * Czs;

    const int t = threadIdx.x;
    const int lane = t & 63;
    const int w = t >> 6;
    const int bm = blockIdx.y * 128, bn = blockIdx.x * 128;

    __shared__ u16 Ahs[128 * 40];
    __shared__ u16 Als[128 * 40];
    __shared__ u16 Bhs[128 * 40];
    __shared__ u16 Bls[128 * 40];

    f32x4 acc[4][4];
#pragma unroll
    for (int i = 0; i < 4; i++)
#pragma unroll
        for (int j = 0; j < 4; j++) acc[i][j] = (f32x4){0.f, 0.f, 0.f, 0.f};

    const int wm = (w >> 1) * 64, wn = (w & 1) * 64;
    const int fr = lane & 15, fgb = lane >> 4;
    const bool ag = (Acs == 1), bg = (Brs == 1);
    const int K8 = (K + 7) & ~7;
    const int rloc = lane >> 2, csl = lane & 3;   // glds: 4 lanes per 64B row, 16B chunks

    // fragment offsets (u16 index), layout per method
    int aoff[4], boff[4];
#pragma unroll
    for (int f = 0; f < 4; f++) {
        int ra = wm + f * 16 + fr;
        aoff[f] = ag ? (ra * 32 + ((fgb ^ ((ra >> 1) & 3)) << 3))
                     : (ra * 40 + (((fgb ^ (ra >> 3)) & 3) << 3));
        int rb = wn + f * 16 + fr;
        boff[f] = bg ? (rb * 32 + ((fgb ^ ((rb >> 1) & 3)) << 3))
                     : (rb * 40 + (((fgb ^ (rb >> 3)) & 3) << 3));
    }

    for (int k0 = 0; k0 < K; k0 += 32) {
        // ---- stage A ----
        if (ag) {
#pragma unroll
            for (int inst = 0; inst < 2; ++inst) {
                int r = w * 32 + inst * 16 + rloc;
                int gr = bm + r; if (gr > M - 1) gr = M - 1;
                int gk = k0 + 8 * (csl ^ ((r >> 1) & 3));
                const u16* sh = zp; const u16* sl = zp;
                if (gk < K8) { size_t o = (size_t)gr * Ars + gk; sh = Ah + o; sl = Al + o; }
                glds16(sh, &Ahs[(w * 32 + inst * 16) * 32]);
                glds16(sl, &Als[(w * 32 + inst * 16) * 32]);
            }
        } else {  // R: Ars==1
            int ml = (t & 63) * 2;
            int kg = t >> 6;
            int gr0 = bm + ml;     if (gr0 > M - 1) gr0 = M - 1;
            int gr1 = bm + ml + 1; if (gr1 > M - 1) gr1 = M - 1;
            bool pair = (gr1 == gr0 + 1);
            u32 vah[8], val8[8];
#pragma unroll
            for (int i = 0; i < 8; i++) {
                int kk = kg + 4 * i;
                int gk = k0 + kk;
                u32 vh = 0, vl = 0;
                if (gk < K) {
                    size_t o = (size_t)gk * Acs + gr0;
                    if (pair) { vh = *(const u32*)(Ah + o); vl = *(const u32*)(Al + o); }
                    else {
                        vh = Ah[o]; vl = Al[o];
                        u32 h1 = Ah[(size_t)gk * Acs + gr1], l1 = Al[(size_t)gk * Acs + gr1];
                        vh |= h1 << 16; vl |= l1 << 16;
                    }
                }
                vah[i] = vh; val8[i] = vl;
            }
#pragma unroll
            for (int i = 0; i < 8; i++) {
                int kk = kg + 4 * i;
                int blk = (kk >> 3) & 3;
                int s0 = ml * 40 + (((blk ^ (ml >> 3)) & 3) << 3) + (kk & 7);
                int s1 = (ml + 1) * 40 + (((blk ^ ((ml + 1) >> 3)) & 3) << 3) + (kk & 7);
                Ahs[s0] = (u16)vah[i]; Ahs[s1] = (u16)(vah[i] >> 16);
                Als[s0] = (u16)val8[i]; Als[s1] = (u16)(val8[i] >> 16);
            }
        }
        // ---- stage B ----
        if (bg) {
#pragma unroll
            for (int inst = 0; inst < 2; ++inst) {
                int cidx = w * 32 + inst * 16 + rloc;
                int gj = bn + cidx; if (gj > N - 1) gj = N - 1;
                int gk = k0 + 8 * (csl ^ ((cidx >> 1) & 3));
                const u16* sh = zp; const u16* sl = zp;
                if (gk < K8) { size_t o = (size_t)gj * Bcs + gk; sh = Bh + o; sl = Bl + o; }
                glds16(sh, &Bhs[(w * 32 + inst * 16) * 32]);
                glds16(sl, &Bls[(w * 32 + inst * 16) * 32]);
            }
        } else {  // R: Bcs==1
            int jl = (t & 63) * 2;
            int kg = t >> 6;
            int gj0 = bn + jl;     if (gj0 > N - 1) gj0 = N - 1;
            int gj1 = bn + jl + 1; if (gj1 > N - 1) gj1 = N - 1;
            bool pair = (gj1 == gj0 + 1);
            u32 vbh[8], vbl[8];
#pragma unroll
            for (int i = 0; i < 8; i++) {
                int kk = kg + 4 * i;
                int gk = k0 + kk;
                u32 vh = 0, vl = 0;
                if (gk < K) {
                    size_t o = (size_t)gk * Brs + gj0;
                    if (pair) { vh = *(const u32*)(Bh + o); vl = *(const u32*)(Bl + o); }
                    else {
                        vh = Bh[o]; vl = Bl[o];
                        u32 h1 = Bh[(size_t)gk * Brs + gj1], l1 = Bl[(size_t)gk * Brs + gj1];
                        vh |= h1 << 16; vl |= l1 << 16;
                    }
                }
                vbh[i] = vh; vbl[i] = vl;
            }
#pragma unroll
            for (int i = 0; i < 8; i++) {
                int kk = kg + 4 * i;
                int blk = (kk >> 3) & 3;
                int s0 = jl * 40 + (((blk ^ (jl >> 3)) & 3) << 3) + (kk & 7);
                int s1 = (jl + 1) * 40 + (((blk ^ ((jl + 1) >> 3)) & 3) << 3) + (kk & 7);
                Bhs[s0] = (u16)vbh[i]; Bhs[s1] = (u16)(vbh[i] >> 16);
                Bls[s0] = (u16)vbl[i]; Bls[s1] = (u16)(vbl[i] >> 16);
            }
        }
        __syncthreads();   // compiler emits vmcnt(0)+lgkmcnt(0) here: glds + ds_writes land

        // 3 source-level passes (NO scheduling intrinsics): peak frag live 48 VGPR not 64.
        {
            bf16x8 fah[4], fbh[4];
#pragma unroll
            for (int f = 0; f < 4; f++) {
                fah[f] = *(const bf16x8*)(Ahs + aoff[f]);
                fbh[f] = *(const bf16x8*)(Bhs + boff[f]);
            }
#pragma unroll
            for (int i = 0; i < 4; i++)
#pragma unroll
                for (int j = 0; j < 4; j++)
                    acc[i][j] = __builtin_amdgcn_mfma_f32_16x16x32_bf16(fah[i], fbh[j], acc[i][j], 0, 0, 0);
            bf16x8 fbl[4];
#pragma unroll
            for (int f = 0; f < 4; f++) fbl[f] = *(const bf16x8*)(Bls + boff[f]);
#pragma unroll
            for (int i = 0; i < 4; i++)
#pragma unroll
                for (int j = 0; j < 4; j++)
                    acc[i][j] = __builtin_amdgcn_mfma_f32_16x16x32_bf16(fah[i], fbl[j], acc[i][j], 0, 0, 0);
            bf16x8 fal[4];
#pragma unroll
            for (int f = 0; f < 4; f++) fal[f] = *(const bf16x8*)(Als + aoff[f]);
#pragma unroll
            for (int i = 0; i < 4; i++)
#pragma unroll
                for (int j = 0; j < 4; j++)
                    acc[i][j] = __builtin_amdgcn_mfma_f32_16x16x32_bf16(fal[i], fbh[j], acc[i][j], 0, 0, 0);
        }
        __syncthreads();
    }

    const float zs = zscale ? zscale[z] : 1.0f;
#pragma unroll
    for (int i = 0; i < 4; i++) {
#pragma unroll
        for (int r = 0; r < 4; r++) {
            int grow = bm + wm + i * 16 + (lane >> 4) * 4 + r;   // D row = (lane>>4)*4+reg
            if (grow >= M) continue;
            float bval = bias ? bias[grow] : 0.0f;
            size_t rowoff = czoff + (size_t)grow * Crs;
#pragma unroll
            for (int j = 0; j < 4; j++) {
                int gcol = bn + wn + j * 16 + fr;                 // D col = lane&15
                if (gcol >= N) continue;
                size_t off = rowoff + (size_t)gcol * Ccs;
                float v = acc[i][j][r] * zs + bval;
                if (biasN) v += biasN[gcol];
                if (resid) v += resid[off];
                if (flags & FLAG_ACC) v += C[off];
                if (flags & FLAG_GELU) v = gelu_f(v);
                if (flags & FLAG_F32) C[off] = v;
                if (flags & FLAG_BF16) {
                    u16 h, l; split_f(v, h, l);
                    Ch[off] = h; Cl[off] = l;
                }
            }
        }
    }
}

static inline void launch_gemm(hipStream_t s,
    const float* A, int Ars, int Acs, int Azs, int Aps,
    const float* B, int Brs, int Bcs, int Bzs, int Bps,
    float* C, int Crs, int Ccs, int Czs, int Cps,
    const float* bias, const float* zscale, const float* resid,
    int M, int N, int K, int Zin, int nplanes, int flags)
{
    dim3 grid((N + 127) / 128, (M + 127) / 128, Zin * nplanes);
    hipLaunchKernelGGL(gemm_f32, grid, dim3(256), 0, s,
                       A, Ars, Acs, Azs, Aps, B, Brs, Bcs, Bzs, Bps,
                       C, Crs, Ccs, Czs, Cps, bias, zscale, resid,
                       M, N, K, Zin, flags);
}

static inline void launch_gemm16(hipStream_t s,
    const u16* Ah, const u16* Al, int Ars, int Acs, int Azs, int Aps,
    const u16* Bh, const u16* Bl, int Brs, int Bcs, int Bzs, int Bps,
    float* C, u16* Ch, u16* Cl, int Crs, int Ccs, int Czs, int Cps,
    const float* bias, const float* biasN, const float* zscale, const float* resid,
    const u16* zp, int M, int N, int K, int Zin, int nplanes, int flags)
{
    dim3 grid((N + 127) / 128, (M + 127) / 128, Zin * nplanes);
    hipLaunchKernelGGL(gemm_bf16, grid, dim3(256), 0, s,
                       Ah, Al, Ars, Acs, Azs, Aps, Bh, Bl, Brs, Bcs, Bzs, Bps,
                       C, Ch, Cl, Crs, Ccs, Czs, Cps, bias, biasN, zscale, resid, zp,
                       M, N, K, Zin, flags);
}

extern "C" void kernel_launch(void* const* d_in, const int* in_sizes, int n_in,
                              void* d_out, int out_size, void* d_ws, size_t ws_size,
                              hipStream_t stream)
{
    const float* x      = (const float*)d_in[0];
    const float* w_enc  = (const float*)d_in[1];
    const float* b_enc  = (const float*)d_in[2];
    const float* pos    = (const float*)d_in[3];
    const float* w_spec = (const float*)d_in[4];
    const float* b_spec = (const float*)d_in[5];
    const float* w_is   = (const float*)d_in[6];
    const float* b_is   = (const float*)d_in[7];
    const float* w_f1   = (const float*)d_in[8];
    const float* b_f1   = (const float*)d_in[9];
    const float* w_f2   = (const float*)d_in[10];
    const float* b_f2   = (const float*)d_in[11];
    const float* w_dec  = (const float*)d_in[12];
    const float* b_dec  = (const float*)d_in[13];
    float* out = (float*)d_out;

    // ---- workspace layout (bytes); total ~451 MB ----
    char* base = (char*)d_ws;
    size_t off = 0;
    auto alloc = [&](size_t bytes) { size_t o = off; off += (bytes + 255) & ~(size_t)255; return o; };
    u16* Pah = (u16*)(base + alloc(12056048));   // 181*33304 u16
    u16* Pal = (u16*)(base + alloc(12056048));
    u16* Psh = (u16*)(base + alloc(12056048));
    u16* Psl = (u16*)(base + alloc(12056048));
    u16* Eh  = (u16*)(base + alloc(260640));     // 2*PIX u16
    u16* El  = (u16*)(base + alloc(260640));
    u16* DtTh = (u16*)(base + alloc(276480));    // 360*384 u16
    u16* DtTl = (u16*)(base + alloc(276480));
    float* wqs = (float*)(base + alloc(724));
    u16* zp  = (u16*)(base + alloc(256));        // 16B zero page (k-tail source)
    // spectral bf16 pair bufs, ONE contiguous block (hmlpT overlay needs contiguity)
    u16* SP  = (u16*)(base + alloc(134189056));  // 4 * PLANE-pair u16 regions
    u16* S0h = SP;
    u16* S0l = SP + 16773632;
    u16* S1h = SP + 2 * 16773632;
    u16* S1l = SP + 3 * 16773632;
    u16* hmlpTh = SP;                    // [PIX][512] u16, spectral bufs dead by MLP time
    u16* hmlpTl = SP + 33361920;
    float* xn  = (float*)(base + alloc(66723840));   // fp32 [c][p] (fc2 residual)
    u16* xnTh = (u16*)(base + alloc(33361920));      // transposed pair [p][c]
    u16* xnTl = (u16*)(base + alloc(33361920));
    float* hbuf = (float*)(base + alloc(66723840));
    float* tA   = (float*)(base + alloc(66723840));
    u16* wth = (u16*)tA;                 // wt pair overlays tA; dead once iDFT writes tA
    u16* wtl = wth + 11862016;           // 181*65536
    u16* wish = (u16*)(base + alloc(131072));
    u16* wisl = (u16*)(base + alloc(131072));
    u16* wf1h = (u16*)(base + alloc(262144));
    u16* wf1l = (u16*)(base + alloc(262144));
    u16* wf2h = (u16*)(base + alloc(262144));
    u16* wf2l = (u16*)(base + alloc(262144));

    init_legendre<<<(181 * 181 + 255) / 256, 256, 0, stream>>>(Pah, Pal, Psh, Psl);
    init_trig<<<(181 * 360 + 255) / 256, 256, 0, stream>>>(Eh, El, DtTh, DtTl, wqs, zp);

    // encoder: h = w_enc*x + b_enc + pos_emb  (K=26, memory-bound: keep fp32 GEMM)
    launch_gemm(stream, w_enc, 26, 1, 0, 0,  x, PIXg, 1, 0, 0,  hbuf, PIXg, 1, 0, 0,
                b_enc, nullptr, pos, EMBg, PIXg, 26, 1, 1, 0);

    for (int L = 0; L < 4; ++L) {
        const float* wsp = w_spec + (size_t)L * EMBg * EMBg * 181;
        const float* bsp = b_spec + (size_t)L * EMBg;
        const float* wis = w_is   + (size_t)L * EMBg * EMBg;
        const float* bis = b_is   + (size_t)L * EMBg;
        const float* wf1 = w_f1   + (size_t)L * MHIDg * EMBg;
        const float* bf1 = b_f1   + (size_t)L * MHIDg;
        const float* wf2 = w_f2   + (size_t)L * EMBg * MHIDg;
        const float* bf2 = b_f2   + (size_t)L * EMBg;

        transpose_wspec<<<dim3(6, 8, 256), 256, 0, stream>>>(wsp, wth, wtl);
        split_bf16<<<(65536 + 255) / 256, 256, 0, stream>>>(wis, wish, wisl, 65536);
        split_bf16<<<(131072 + 255) / 256, 256, 0, stream>>>(wf1, wf1h, wf1l, 131072);
        split_bf16<<<(131072 + 255) / 256, 256, 0, stream>>>(wf2, wf2h, wf2l, 131072);

        // xn = LN(h): fp32 [c][p] + transposed pair [p][c]
        ln_kernel<<<1019, 256, 0, stream>>>(hbuf, xn, xnTh, xnTl);

        // DFT (z=lat k, planes cos/sin): S0[m][k][c] = (sum_n E[m][n]*xnT[k*360+n][c])*wqs[k]
        // A=E: G (k=n contig). B=xnT: R (panel contiguous).
        launch_gemm16(stream, Eh, El, 360, 1, 0, PIXg,  xnTh, xnTl, 256, 1, 92160, 0,
                      nullptr, S0h, S0l, 46336, 1, 256, PLANEg,
                      nullptr, nullptr, wqs, nullptr, zp, 181, 256, 360, 181, 2, FLAG_BF16);
        // analysis (z=m): S1[l][m][c] = sum_k Pa[m][l][k]*S0[m][k][c]
        // A=Pa: G. B=S0: R (contiguous 92KB panel per z).
        launch_gemm16(stream, Pah, Pal, PKSTR, 1, PMSTR2, 0,  S0h, S0l, 256, 1, 46336, PLANEg,
                      nullptr, S1h, S1l, 46336, 1, 256, PLANEg,
                      nullptr, nullptr, nullptr, nullptr, zp, 181, 256, 181, 181, 2, FLAG_BF16);
        // dhconv (z=l): S0'[m][l][o] = sum_i S1[l][m][i]*wt[l][i][o]
        // A=S1: G (k=i contig). B=wt: R (contiguous 128KB panel per z).
        launch_gemm16(stream, S1h, S1l, 256, 1, 46336, PLANEg,  wth, wtl, 256, 1, 65536, 0,
                      nullptr, S0h, S0l, 46336, 1, 256, PLANEg,
                      nullptr, nullptr, nullptr, nullptr, zp, 181, 256, 256, 181, 2, FLAG_BF16);
        // synthesis (z=m): S1'[k][pl*181+m][c] = sum_l Ps[m][k][l]*S0'[m][l][c]
        // A=Ps: G. B=S0': R (contiguous panel).
        launch_gemm16(stream, Psh, Psl, PKSTR, 1, PMSTR2, 0,  S0h, S0l, 256, 1, 46336, PLANEg,
                      nullptr, S1h, S1l, 92672, 1, 256, 46336,
                      nullptr, nullptr, nullptr, nullptr, zp, 181, 256, 181, 181, 2, FLAG_BF16);
        // iDFT (z=lat k): tA[c][k*360+n] = sum_{m'} S1'[k][m'][c]*DtT[n][m']
        // A=S1': R (contiguous 185KB panel per z). B=DtT: G (k=m' contig, 384-padded).
        launch_gemm16(stream, S1h, S1l, 1, 256, 92672, 0,  DtTh, DtTl, 1, 384, 0, 0,
                      tA, nullptr, nullptr, PIXg, 1, 360, 0,
                      nullptr, nullptr, nullptr, nullptr, zp, 256, 360, 362, 181, 1, FLAG_F32);
        // inner skip into tA: tA += wis*xn + bis   (A: G; B=xnT: G)
        launch_gemm16(stream, wish, wisl, 256, 1, 0, 0,  xnTh, xnTl, 1, 256, 0, 0,
                      tA, nullptr, nullptr, PIXg, 1, 0, 0,
                      bis, nullptr, nullptr, nullptr, zp, 256, PIXg, 256, 1, 1, FLAG_F32 | FLAG_ACC);
        // x1 = gelu(tA + b_spec) in place
        gelu_bias<<<16290, 256, 0, stream>>>(tA, bsp);
        // x2 = LN(x1): transposed pair only (fc1 consumes [p][c]); xn fp32 preserved
        ln_kernel<<<1019, 256, 0, stream>>>(tA, nullptr, xnTh, xnTl);
        // fc1 TRANSPOSED: hmlpT[p][h] = gelu(sum_i xnT[p][i]*wf1[h][i] + bf1[h])
        // M=PIX rows p, N=512 cols h, col-bias bf1. A=xnT: G; B=wf1: G.
        launch_gemm16(stream, xnTh, xnTl, 256, 1, 0, 0,  wf1h, wf1l, 1, 256, 0, 0,
                      nullptr, hmlpTh, hmlpTl, 512, 1, 0, 0,
                      nullptr, bf1, nullptr, nullptr, zp, PIXg, 512, 256, 1, 1, FLAG_BF16 | FLAG_GELU);
        // fc2 + residual xn -> h: hbuf[c][p] = sum_h wf2[c][h]*hmlpT[p][h] + bf2 + xn
        // A=wf2: G; B=hmlpT: G.
        launch_gemm16(stream, wf2h, wf2l, 512, 1, 0, 0,  hmlpTh, hmlpTl, 1, 512, 0, 0,
                      hbuf, nullptr, nullptr, PIXg, 1, 0, 0,
                      bf2, nullptr, nullptr, xn, zp, EMBg, PIXg, 512, 1, 1, FLAG_F32);
    }

    // decoder: out = w_dec[:, :256]*h + w_dec[:, 256:]*x + b_dec  (tiny M: fp32 GEMM)
    launch_gemm(stream, w_dec, 282, 1, 0, 0,  hbuf, PIXg, 1, 0, 0,  out, PIXg, 1, 0, 0,
                b_dec, nullptr, nullptr, 26, PIXg, 256, 1, 1, 0);
    launch_gemm(stream, w_dec + 256, 282, 1, 0, 0,  x, PIXg, 1, 0, 0,  out, PIXg, 1, 0, 0,
                nullptr, nullptr, nullptr, 26, PIXg, 26, 1, 1, FLAG_ACC);
}

// Round 9
// 8614.396 us; speedup vs baseline: 2.5836x; 1.0082x over previous
//
#include <hip/hip_runtime.h>
#include <math.h>

#define NLATg 181
#define NLONg 360
#define PIXg  65160        // 181*360
#define EMBg  256
#define MHIDg 512
#define PLANEg 8386816     // 181*46336
#define PKSTR 184          // padded k-extent stride in Pa/Ps (mult of 8, zero-padded)
#define PMSTR2 33304       // 181*184, per-m stride in Pa/Ps
#define LBUF 5120          // u16 per LDS tile buffer (128*40)

#define FLAG_GELU 1
#define FLAG_ACC  2
#define FLAG_F32  4
#define FLAG_BF16 8

typedef unsigned short u16;
typedef unsigned int   u32;
typedef __attribute__((ext_vector_type(8))) short bf16x8;
typedef __attribute__((ext_vector_type(4))) float f32x4;

__device__ __forceinline__ float gelu_f(float x) {
    return 0.5f * x * (1.0f + erff(x * 0.70710678118654752440f));
}

// fp32 -> (hi, lo) truncated bf16 pair: v ~= hi + lo with ~2^-16 relative error.
__device__ __forceinline__ void split_f(float v, u16& h, u16& l) {
    u32 u = __float_as_uint(v);
    h = (u16)(u >> 16);
    float hf = __uint_as_float(u & 0xFFFF0000u);
    l = (u16)(__float_as_uint(v - hf) >> 16);
}

// async global->LDS, 16B per lane; LDS dest = wave-uniform base + lane*16 (HW rule)
__device__ __forceinline__ void glds16(const u16* g, u16* l) {
    __builtin_amdgcn_global_load_lds((const __attribute__((address_space(1))) u32*)g,
                                     (__attribute__((address_space(3))) u32*)l, 16, 0, 0);
}

// ---------------- init kernels (run every call; graph-capture safe) ----------------

// Legendre fp64 recurrence -> TWO layouts, bf16 hi/lo pairs, k-extent padded to 184 w/ zeros:
//   Pa[m][l][klat]  (analysis A: contract over klat, k-contiguous)
//   Ps[m][klat][l]  (synthesis A: contract over l,  k-contiguous)
__global__ __launch_bounds__(256) void init_legendre(u16* __restrict__ Pah, u16* __restrict__ Pal,
                                                     u16* __restrict__ Psh, u16* __restrict__ Psl) {
    int idx = blockIdx.x * 256 + threadIdx.x;
    if (idx >= 181 * 181) return;
    int m = idx / 181, k = idx % 181;
    // zero pads: Pa[m][l][181+k] (k<3 threads cover all l); Ps[m][k][181..183]
    if (k < 3) {
        for (int l = 0; l < 181; ++l) {
            size_t o = (size_t)m * PMSTR2 + (size_t)l * PKSTR + 181 + k;
            Pah[o] = 0; Pal[o] = 0;
        }
    }
    for (int j = 181; j < PKSTR; ++j) {
        size_t o = (size_t)m * PMSTR2 + (size_t)k * PKSTR + j;
        Psh[o] = 0; Psl[o] = 0;
    }
    double theta = M_PI * (double)k / 180.0;
    double ct = cos(theta), st = sin(theta);
    double pmm = sqrt(1.0 / (4.0 * M_PI));
    for (int j = 1; j <= m; ++j) pmm *= -sqrt((2.0 * j + 1.0) / (2.0 * j)) * st;
    u16 h, lo;
    auto emit = [&](int l, double v) {
        split_f((float)v, h, lo);
        size_t oa = (size_t)m * PMSTR2 + (size_t)l * PKSTR + k;
        size_t os = (size_t)m * PMSTR2 + (size_t)k * PKSTR + l;
        Pah[oa] = h; Pal[oa] = lo;
        Psh[os] = h; Psl[os] = lo;
    };
    for (int l2 = 0; l2 < m; ++l2) emit(l2, 0.0);
    emit(m, pmm);
    if (m + 1 < 181) {
        double pl1 = sqrt(2.0 * m + 3.0) * ct * pmm;
        emit(m + 1, pl1);
        double pl2 = pmm;
        for (int ll = m + 2; ll < 181; ++ll) {
            double L = ll, M2 = m;
            double a = sqrt((4.0 * L * L - 1.0) / (L * L - M2 * M2));
            double b = sqrt(((2.0 * L + 1.0) * (L - 1.0 + M2) * (L - 1.0 - M2)) /
                            ((2.0 * L - 3.0) * (L * L - M2 * M2)));
            double p = a * ct * pl1 - b * pl2;
            emit(ll, p);
            pl2 = pl1; pl1 = p;
        }
    }
}

// E[m][n] (cos; +PIX: -sin) unchanged; DtT[n][m'] transposed iDFT matrix, m'-stride 384
// zero-padded (m' in [362,384)); wqs; 16B zero page.
__global__ __launch_bounds__(256) void init_trig(u16* __restrict__ Eh, u16* __restrict__ El,
                                                 u16* __restrict__ DtTh, u16* __restrict__ DtTl,
                                                 float* __restrict__ wqs, u16* __restrict__ zpb) {
    int idx = blockIdx.x * 256 + threadIdx.x;
    if (idx < 8) zpb[idx] = 0;
    if (idx < 181) {
        double theta = M_PI * (double)idx / 180.0;
        wqs[idx] = (float)(2.0 * M_PI * (M_PI / 180.0) * sin(theta) / 360.0);
    }
    if (idx >= 181 * 360) return;
    int m = idx / 360, n = idx % 360;
    int a = (m * n) % 360;           // exact angle reduction
    double ang = M_PI * (double)a / 180.0;
    double c = cos(ang), s = sin(ang);
    u16 h, l;
    split_f((float)c, h, l);        Eh[idx] = h;        El[idx] = l;
    split_f((float)(-s), h, l);     Eh[PIXg + idx] = h; El[PIXg + idx] = l;
    double cm = (m == 0 || m == 180) ? 1.0 : 2.0;
    split_f((float)(cm * c), h, l);
    DtTh[(size_t)n * 384 + m] = h;        DtTl[(size_t)n * 384 + m] = l;
    split_f((float)(-cm * s), h, l);
    DtTh[(size_t)n * 384 + 181 + m] = h;  DtTl[(size_t)n * 384 + 181 + m] = l;
    if (m == 0) {
        for (int j = 362; j < 384; ++j) { DtTh[(size_t)n * 384 + j] = 0; DtTl[(size_t)n * 384 + j] = 0; }
    }
}

// wt[l][i][o] = W[o][i][l], bf16 pair (o-contiguous writes; dhconv consumes via R-path)
__global__ __launch_bounds__(256) void transpose_wspec(const float* __restrict__ W,
                                                       u16* __restrict__ WTh, u16* __restrict__ WTl) {
    __shared__ float tile[32][33];
    int l0 = blockIdx.x * 32, o0 = blockIdx.y * 32, i = blockIdx.z;
    int c = threadIdx.x & 31, r = threadIdx.x >> 5;
#pragma unroll
    for (int j = 0; j < 4; j++) {
        int row = r + j * 8;
        float v = 0.f;
        if (l0 + c < 181) v = W[(size_t)(o0 + row) * 46336 + i * 181 + (l0 + c)];
        tile[row][c] = v;
    }
    __syncthreads();
#pragma unroll
    for (int j = 0; j < 4; j++) {
        int row = r + j * 8;
        if (l0 + row < 181) {
            u16 h, l; split_f(tile[c][row], h, l);
            size_t o = (size_t)(l0 + row) * 65536 + i * 256 + (o0 + c);
            WTh[o] = h; WTl[o] = l;
        }
    }
}

// generic fp32 -> bf16-pair splitter (weights)
__global__ __launch_bounds__(256) void split_bf16(const float* __restrict__ in,
                                                  u16* __restrict__ h, u16* __restrict__ l, int n) {
    int i = blockIdx.x * 256 + threadIdx.x;
    if (i >= n) return;
    u16 hh, ll; split_f(in[i], hh, ll);
    h[i] = hh; l[i] = ll;
}

// LayerNorm over channels (256) per pixel; emits optional fp32 [c][p] + TRANSPOSED pair [p][c]
__global__ __launch_bounds__(256) void ln_kernel(const float* __restrict__ X, float* __restrict__ Y,
                                                 u16* __restrict__ YTh, u16* __restrict__ YTl) {
    int p0 = blockIdx.x * 64;
    int t = threadIdx.x;
    int ps = t & 63, cg = t >> 6;
    int p = p0 + ps;
    bool ok = p < PIXg;
    float sum = 0.f, sumsq = 0.f;
    if (ok) {
        for (int c = cg; c < EMBg; c += 4) {
            float v = X[(size_t)c * PIXg + p];
            sum += v; sumsq += v * v;
        }
    }
    __shared__ float s1[4][64];
    __shared__ float s2[4][64];
    s1[cg][ps] = sum; s2[cg][ps] = sumsq;
    __syncthreads();
    float tot  = s1[0][ps] + s1[1][ps] + s1[2][ps] + s1[3][ps];
    float tot2 = s2[0][ps] + s2[1][ps] + s2[2][ps] + s2[3][ps];
    float mu = tot * (1.0f / 256.0f);
    float var = tot2 * (1.0f / 256.0f) - mu * mu;
    float inv = rsqrtf(var + 1e-6f);
    if (ok) {
        for (int c = cg; c < EMBg; c += 4) {
            size_t offp = (size_t)c * PIXg + p;
            float v = (X[offp] - mu) * inv;
            if (Y) Y[offp] = v;
            u16 h, l; split_f(v, h, l);
            size_t ot = (size_t)p * 256 + c;
            YTh[ot] = h; YTl[ot] = l;
        }
    }
}

// x1 = gelu(X + bias[c]) in place, float4 over [256][PIX]
__global__ __launch_bounds__(256) void gelu_bias(float* __restrict__ X, const float* __restrict__ b) {
    int idx = blockIdx.x * 256 + threadIdx.x;   // float4 index
    int c = idx / 16290;                        // PIX/4
    float bv = b[c];
    float4 v = reinterpret_cast<float4*>(X)[idx];
    v.x = gelu_f(v.x + bv); v.y = gelu_f(v.y + bv);
    v.z = gelu_f(v.z + bv); v.w = gelu_f(v.w + bv);
    reinterpret_cast<float4*>(X)[idx] = v;
}

// ---------------- fp32 strided batched GEMM (tiny-K encoder/decoder only) --------------
__global__ __launch_bounds__(256, 2) void gemm_f32(
    const float* __restrict__ A, int Ars, int Acs, int Azs, int Aps,
    const float* __restrict__ B, int Brs, int Bcs, int Bzs, int Bps,
    float* __restrict__ C, int Crs, int Ccs, int Czs, int Cps,
    const float* __restrict__ bias, const float* __restrict__ zscale,
    const float* __restrict__ resid,
    int M, int N, int K, int Zin, int flags)
{
    int z = blockIdx.z;
    if (z >= Zin) { z -= Zin; A += Aps; B += Bps; C += Cps; if (resid) resid += Cps; }
    A += (size_t)z * Azs; B += (size_t)z * Bzs; C += (size_t)z * Czs;
    if (resid) resid += (size_t)z * Czs;

    const int bm = blockIdx.y * 128, bn = blockIdx.x * 128;
    const int t = threadIdx.x;
    const int tx = t & 15, ty = t >> 4;

    __shared__ float As[16][132];
    __shared__ float Bs[16][132];

    float acc[8][8];
#pragma unroll
    for (int i = 0; i < 8; i++)
#pragma unroll
        for (int j = 0; j < 8; j++) acc[i][j] = 0.0f;

    for (int k0 = 0; k0 < K; k0 += 16) {
        if (Acs == 1) {
            int kk = t & 15, r = t >> 4;
            int gk = k0 + kk; bool kv = gk < K;
#pragma unroll
            for (int i = 0; i < 8; i++) {
                int gr = bm + r + i * 16; if (gr > M - 1) gr = M - 1;
                As[kk][r + i * 16] = kv ? A[(size_t)gr * Ars + gk] : 0.f;
            }
        } else {
            int row = t & 127, kb = t >> 7;
            int gr = bm + row; if (gr > M - 1) gr = M - 1;
            size_t base = (size_t)gr * Ars;
#pragma unroll
            for (int i = 0; i < 8; i++) {
                int gk = k0 + kb + i * 2;
                As[kb + i * 2][row] = (gk < K) ? A[base + (size_t)gk * Acs] : 0.f;
            }
        }
        if (Bcs == 1) {
            int col = t & 127, kb = t >> 7;
            int gc = bn + col; if (gc > N - 1) gc = N - 1;
#pragma unroll
            for (int i = 0; i < 8; i++) {
                int gk = k0 + kb + i * 2;
                Bs[kb + i * 2][col] = (gk < K) ? B[(size_t)gk * Brs + gc] : 0.f;
            }
        } else {
            int kk = t & 15, cb = t >> 4;
            int gk = k0 + kk; bool kv = gk < K;
#pragma unroll
            for (int i = 0; i < 8; i++) {
                int gc = bn + cb + i * 16; if (gc > N - 1) gc = N - 1;
                Bs[kk][cb + i * 16] = kv ? B[(size_t)gk * Brs + (size_t)gc * Bcs] : 0.f;
            }
        }
        __syncthreads();
#pragma unroll
        for (int kk = 0; kk < 16; kk++) {
            float4 a0 = *(const float4*)&As[kk][ty * 4];
            float4 a1 = *(const float4*)&As[kk][ty * 4 + 64];
            float4 b0 = *(const float4*)&Bs[kk][tx * 4];
            float4 b1 = *(const float4*)&Bs[kk][tx * 4 + 64];
            float av[8] = {a0.x, a0.y, a0.z, a0.w, a1.x, a1.y, a1.z, a1.w};
            float bv[8] = {b0.x, b0.y, b0.z, b0.w, b1.x, b1.y, b1.z, b1.w};
#pragma unroll
            for (int i = 0; i < 8; i++)
#pragma unroll
                for (int j = 0; j < 8; j++)
                    acc[i][j] = fmaf(av[i], bv[j], acc[i][j]);
        }
        __syncthreads();
    }

    const float zs = zscale ? zscale[z] : 1.0f;
    const bool fastN = (Ccs == 1) && (bn + 128 <= N);
#pragma unroll
    for (int i = 0; i < 8; i++) {
        int gi = bm + ty * 4 + (i & 3) + ((i >> 2) << 6);
        if (gi >= M) continue;
        float bval = bias ? bias[gi] : 0.0f;
        size_t crow = (size_t)gi * (size_t)Crs;
        if (fastN) {
#pragma unroll
            for (int h = 0; h < 2; h++) {
                int gj = bn + tx * 4 + h * 64;
                size_t off = crow + (size_t)gj;
                float4 v;
                v.x = acc[i][h * 4 + 0] * zs + bval;
                v.y = acc[i][h * 4 + 1] * zs + bval;
                v.z = acc[i][h * 4 + 2] * zs + bval;
                v.w = acc[i][h * 4 + 3] * zs + bval;
                if (resid) { float4 r = *(const float4*)&resid[off];
                             v.x += r.x; v.y += r.y; v.z += r.z; v.w += r.w; }
                if (flags & FLAG_GELU) { v.x = gelu_f(v.x); v.y = gelu_f(v.y);
                                         v.z = gelu_f(v.z); v.w = gelu_f(v.w); }
                if (flags & FLAG_ACC)  { float4 c0 = *(const float4*)&C[off];
                                         v.x += c0.x; v.y += c0.y; v.z += c0.z; v.w += c0.w; }
                *(float4*)&C[off] = v;
            }
        } else {
#pragma unroll
            for (int j = 0; j < 8; j++) {
                int gj = bn + tx * 4 + (j & 3) + ((j >> 2) << 6);
                if (gj >= N) continue;
                size_t off = crow + (size_t)gj * (size_t)Ccs;
                float v = acc[i][j] * zs + bval;
                if (resid) v += resid[off];
                if (flags & FLAG_GELU) v = gelu_f(v);
                if (flags & FLAG_ACC) v += C[off];
                C[off] = v;
            }
        }
    }
}

// ---------------- bf16x2-split MFMA GEMM (fp32-grade via 3 MFMA terms) ----------------
// C = (Ah+Al)(Bh+Bl) ~= Ah*Bh + Ah*Bl + Al*Bh, fp32 accumulate in matrix cores.
// Staging: G (k-contiguous) via global_load_lds into linear [128][32] with chunk-XOR
// x(row)=(row>>1)&3 on the per-lane GLOBAL source and on the fragment read =>
// conflict-free ds_read_b128 (r7 PMC: SQ_LDS_BANK_CONFLICT = 0).
// R (k-strided) via register gather + ds_write into [128][40] XOR-swizzled layout.
// r8/r9: 2-PHASE DOUBLE-BUFFERED PREFETCH (plain HIP, T3-minimum): STAGE(buf^1, t+1) is
// issued BEFORE the frag-reads+MFMA of step t; the single end-of-step __syncthreads
// (vmcnt(0)+lgkmcnt(0)) then only waits the latency residue. LDS 2x40KB=80KB -> still
// 2 blocks/CU (the VGPR+AGPR limit). Plus bijective XCD swizzle (m204) for L2 locality.
// (r8 bench was an infra failure — container acquisition; kernel resubmitted unchanged.)
// HISTORY (do not regress):
//  - r1: launch_bounds(256,2) pinned VGPR=128 -> acc spill, 928MB scratch/dispatch.
//  - r2: sched_barrier(0) between MFMA clusters -> intermittent silent corruption. NO
//    scheduling intrinsics in this kernel, ever. (Source-level ordering only.)
//  - r3/r4: register staging serialized loads (compiler sinks loads to ds_write uses).
//  - r5/r7: glds staging, (256,1), VGPR 156-176, 2 blocks/CU, ~322us fc1: each K-step
//    pays full ~900cy latency (stage->vmcnt(0)->compute serial chain), 12K cy/step.
//  - r6: (256,3) forced VGPR=84 -> total spill (2.8GB scratch/dispatch, 886us).
//    Occupancy CANNOT be bought with launch_bounds on this body.
__global__ __launch_bounds__(256, 1) void gemm_bf16(
    const u16* __restrict__ Ah, const u16* __restrict__ Al,
    int Ars, int Acs, int Azs, int Aps,
    const u16* __restrict__ Bh, const u16* __restrict__ Bl,
    int Brs, int Bcs, int Bzs, int Bps,
    float* __restrict__ C, u16* __restrict__ Ch, u16* __restrict__ Cl,
    int Crs, int Ccs, int Czs, int Cps,
    const float* __restrict__ bias, const float* __restrict__ biasN,
    const float* __restrict__ zscale, const float* __restrict__ resid,
    const u16* __restrict__ zp,
    int M, int N, int K, int Zin, int flags)
{
    // ---- bijective XCD swizzle (m204): chunked work-linear -> same-XCD locality ----
    unsigned gx = gridDim.x, gy = gridDim.y;
    unsigned nwg = gx * gy * gridDim.z;
    unsigned hw = (blockIdx.z * gy + blockIdx.y) * gx + blockIdx.x;
    unsigned wid2 = hw;
    if (nwg >= 16) {
        unsigned q = nwg >> 3, r2 = nwg & 7;
        unsigned xcd = hw & 7, sl = hw >> 3;
        wid2 = (xcd < r2 ? xcd * (q + 1) : r2 * (q + 1) + (xcd - r2) * q) + sl;
    }
    unsigned bxu = wid2 % gx; unsigned t2 = wid2 / gx;
    unsigned byu = t2 % gy;   unsigned bzu = t2 / gy;

    int z = (int)bzu;
    if (z >= Zin) {
        z -= Zin;
        Ah += Aps; Al += Aps; Bh += Bps; Bl += Bps;
        if (C) C += Cps;
        if (Ch) Ch += Cps;
        if (Cl) Cl += Cps;
        if (resid) resid += Cps;
    }
    Ah += (size_t)z * Azs; Al += (size_t)z * Azs;
    Bh += (size_t)z * Bzs; Bl += (size_t)z * Bzs;
    const size_t czoff = (size_t)z * Czs;

    const int t = threadIdx.x;
    const int lane = t & 63;
    const int w = t >> 6;
    const int bm = (int)byu * 128, bn = (int)bxu * 128;

    __shared__ u16 Ahs[2 * LBUF];
    __shared__ u16 Als[2 * LBUF];
    __shared__ u16 Bhs[2 * LBUF];
    __shared__ u16 Bls[2 * LBUF];

    f32x4 acc[4][4];
#pragma unroll
    for (int i = 0; i < 4; i++)
#pragma unroll
        for (int j = 0; j < 4; j++) acc[i][j] = (f32x4){0.f, 0.f, 0.f, 0.f};

    const int wm = (w >> 1) * 64, wn = (w & 1) * 64;
    const int fr = lane & 15, fgb = lane >> 4;
    const bool ag = (Acs == 1), bg = (Brs == 1);
    const int K8 = (K + 7) & ~7;
    const int rloc = lane >> 2, csl = lane & 3;   // glds: 4 lanes per 64B row, 16B chunks

    // fragment offsets (u16 index), layout per method
    int aoff[4], boff[4];
#pragma unroll
    for (int f = 0; f < 4; f++) {
        int ra = wm + f * 16 + fr;
        aoff[f] = ag ? (ra * 32 + ((fgb ^ ((ra >> 1) & 3)) << 3))
                     : (ra * 40 + (((fgb ^ (ra >> 3)) & 3) << 3));
        int rb = wn + f * 16 + fr;
        boff[f] = bg ? (rb * 32 + ((fgb ^ ((rb >> 1) & 3)) << 3))
                     : (rb * 40 + (((fgb ^ (rb >> 3)) & 3) << 3));
    }

    // stage one K-step tile into buffer offset bo (0 or LBUF)
    auto stage = [&](int bo, int k0) {
        // ---- stage A ----
        if (ag) {
#pragma unroll
            for (int inst = 0; inst < 2; ++inst) {
                int r = w * 32 + inst * 16 + rloc;
                int gr = bm + r; if (gr > M - 1) gr = M - 1;
                int gk = k0 + 8 * (csl ^ ((r >> 1) & 3));
                const u16* sh = zp; const u16* sl = zp;
                if (gk < K8) { size_t o = (size_t)gr * Ars + gk; sh = Ah + o; sl = Al + o; }
                glds16(sh, &Ahs[bo + (w * 32 + inst * 16) * 32]);
                glds16(sl, &Als[bo + (w * 32 + inst * 16) * 32]);
            }
        } else {  // R: Ars==1
            int ml = (t & 63) * 2;
            int kg = t >> 6;
            int gr0 = bm + ml;     if (gr0 > M - 1) gr0 = M - 1;
            int gr1 = bm + ml + 1; if (gr1 > M - 1) gr1 = M - 1;
            bool pair = (gr1 == gr0 + 1);
            u32 vah[8], val8[8];
#pragma unroll
            for (int i = 0; i < 8; i++) {
                int kk = kg + 4 * i;
                int gk = k0 + kk;
                u32 vh = 0, vl = 0;
                if (gk < K) {
                    size_t o = (size_t)gk * Acs + gr0;
                    if (pair) { vh = *(const u32*)(Ah + o); vl = *(const u32*)(Al + o); }
                    else {
                        vh = Ah[o]; vl = Al[o];
                        u32 h1 = Ah[(size_t)gk * Acs + gr1], l1 = Al[(size_t)gk * Acs + gr1];
                        vh |= h1 << 16; vl |= l1 << 16;
                    }
                }
                vah[i] = vh; val8[i] = vl;
            }
#pragma unroll
            for (int i = 0; i < 8; i++) {
                int kk = kg + 4 * i;
                int blk = (kk >> 3) & 3;
                int s0 = bo + ml * 40 + (((blk ^ (ml >> 3)) & 3) << 3) + (kk & 7);
                int s1 = bo + (ml + 1) * 40 + (((blk ^ ((ml + 1) >> 3)) & 3) << 3) + (kk & 7);
                Ahs[s0] = (u16)vah[i]; Ahs[s1] = (u16)(vah[i] >> 16);
                Als[s0] = (u16)val8[i]; Als[s1] = (u16)(val8[i] >> 16);
            }
        }
        // ---- stage B ----
        if (bg) {
#pragma unroll
            for (int inst = 0; inst < 2; ++inst) {
                int cidx = w * 32 + inst * 16 + rloc;
                int gj = bn + cidx; if (gj > N - 1) gj = N - 1;
                int gk = k0 + 8 * (csl ^ ((cidx >> 1) & 3));
                const u16* sh = zp; const u16* sl = zp;
                if (gk < K8) { size_t o = (size_t)gj * Bcs + gk; sh = Bh + o; sl = Bl + o; }
                glds16(sh, &Bhs[bo + (w * 32 + inst * 16) * 32]);
                glds16(sl, &Bls[bo + (w * 32 + inst * 16) * 32]);
            }
        } else {  // R: Bcs==1
            int jl = (t & 63) * 2;
            int kg = t >> 6;
            int gj0 = bn + jl;     if (gj0 > N - 1) gj0 = N - 1;
            int gj1 = bn + jl + 1; if (gj1 > N - 1) gj1 = N - 1;
            bool pair = (gj1 == gj0 + 1);
            u32 vbh[8], vbl[8];
#pragma unroll
            for (int i = 0; i < 8; i++) {
                int kk = kg + 4 * i;
                int gk = k0 + kk;
                u32 vh = 0, vl = 0;
                if (gk < K) {
                    size_t o = (size_t)gk * Brs + gj0;
                    if (pair) { vh = *(const u32*)(Bh + o); vl = *(const u32*)(Bl + o); }
                    else {
                        vh = Bh[o]; vl = Bl[o];
                        u32 h1 = Bh[(size_t)gk * Brs + gj1], l1 = Bl[(size_t)gk * Brs + gj1];
                        vh |= h1 << 16; vl |= l1 << 16;
                    }
                }
                vbh[i] = vh; vbl[i] = vl;
            }
#pragma unroll
            for (int i = 0; i < 8; i++) {
                int kk = kg + 4 * i;
                int blk = (kk >> 3) & 3;
                int s0 = bo + jl * 40 + (((blk ^ (jl >> 3)) & 3) << 3) + (kk & 7);
                int s1 = bo + (jl + 1) * 40 + (((blk ^ ((jl + 1) >> 3)) & 3) << 3) + (kk & 7);
                Bhs[s0] = (u16)vbh[i]; Bhs[s1] = (u16)(vbh[i] >> 16);
                Bls[s0] = (u16)vbl[i]; Bls[s1] = (u16)(vbl[i] >> 16);
            }
        }
    };

    // prologue: stage step 0 into buffer 0
    stage(0, 0);
    __syncthreads();

    int cur = 0;
    for (int k0 = 0; k0 < K; k0 += 32) {
        // prefetch next K-step into the other buffer (overlaps this step's compute;
        // the end-of-step barrier's vmcnt(0) waits only the residue)
        int nb = cur ^ 1;
        if (k0 + 32 < K) stage(nb * LBUF, k0 + 32);

        const int co = cur * LBUF;
        // 3 source-level passes (NO scheduling intrinsics): peak frag live 48 VGPR not 64.
        {
            bf16x8 fah[4], fbh[4];
#pragma unroll
            for (int f = 0; f < 4; f++) {
                fah[f] = *(const bf16x8*)(Ahs + co + aoff[f]);
                fbh[f] = *(const bf16x8*)(Bhs + co + boff[f]);
            }
#pragma unroll
            for (int i = 0; i < 4; i++)
#pragma unroll
                for (int j = 0; j < 4; j++)
                    acc[i][j] = __builtin_amdgcn_mfma_f32_16x16x32_bf16(fah[i], fbh[j], acc[i][j], 0, 0, 0);
            bf16x8 fbl[4];
#pragma unroll
            for (int f = 0; f < 4; f++) fbl[f] = *(const bf16x8*)(Bls + co + boff[f]);
#pragma unroll
            for (int i = 0; i < 4; i++)
#pragma unroll
                for (int j = 0; j < 4; j++)
                    acc[i][j] = __builtin_amdgcn_mfma_f32_16x16x32_bf16(fah[i], fbl[j], acc[i][j], 0, 0, 0);
            bf16x8 fal[4];
#pragma unroll
            for (int f = 0; f < 4; f++) fal[f] = *(const bf16x8*)(Als + co + aoff[f]);
#pragma unroll
            for (int i = 0; i < 4; i++)
#pragma unroll
                for (int j = 0; j < 4; j++)
                    acc[i][j] = __builtin_amdgcn_mfma_f32_16x16x32_bf16(fal[i], fbh[j], acc[i][j], 0, 0, 0);
        }
        __syncthreads();   // drains prefetch glds/ds_writes AND protects cur-buffer reads
        cur = nb;
    }

    const float zs = zscale ? zscale[z] : 1.0f;
#pragma unroll
    for (int i = 0; i < 4; i++) {
#pragma unroll
        for (int r = 0; r < 4; r++) {
            int grow = bm + wm + i * 16 + (lane >> 4) * 4 + r;   // D row = (lane>>4)*4+reg
            if (grow >= M) continue;
            float bval = bias ? bias[grow] : 0.0f;
            size_t rowoff = czoff + (size_t)grow * Crs;
#pragma unroll
            for (int j = 0; j < 4; j++) {
                int gcol = bn + wn + j * 16 + fr;                 // D col = lane&15
                if (gcol >= N) continue;
                size_t off = rowoff + (size_t)gcol * Ccs;
                float v = acc[i][j][r] * zs + bval;
                if (biasN) v += biasN[gcol];
                if (resid) v += resid[off];
                if (flags & FLAG_ACC) v += C[off];
                if (flags & FLAG_GELU) v = gelu_f(v);
                if (flags & FLAG_F32) C[off] = v;
                if (flags & FLAG_BF16) {
                    u16 h, l; split_f(v, h, l);
                    Ch[off] = h; Cl[off] = l;
                }
            }
        }
    }
}

static inline void launch_gemm(hipStream_t s,
    const float* A, int Ars, int Acs, int Azs, int Aps,
    const float* B, int Brs, int Bcs, int Bzs, int Bps,
    float* C, int Crs, int Ccs, int Czs, int Cps,
    const float* bias, const float* zscale, const float* resid,
    int M, int N, int K, int Zin, int nplanes, int flags)
{
    dim3 grid((N + 127) / 128, (M + 127) / 128, Zin * nplanes);
    hipLaunchKernelGGL(gemm_f32, grid, dim3(256), 0, s,
                       A, Ars, Acs, Azs, Aps, B, Brs, Bcs, Bzs, Bps,
                       C, Crs, Ccs, Czs, Cps, bias, zscale, resid,
                       M, N, K, Zin, flags);
}

static inline void launch_gemm16(hipStream_t s,
    const u16* Ah, const u16* Al, int Ars, int Acs, int Azs, int Aps,
    const u16* Bh, const u16* Bl, int Brs, int Bcs, int Bzs, int Bps,
    float* C, u16* Ch, u16* Cl, int Crs, int Ccs, int Czs, int Cps,
    const float* bias, const float* biasN, const float* zscale, const float* resid,
    const u16* zp, int M, int N, int K, int Zin, int nplanes, int flags)
{
    dim3 grid((N + 127) / 128, (M + 127) / 128, Zin * nplanes);
    hipLaunchKernelGGL(gemm_bf16, grid, dim3(256), 0, s,
                       Ah, Al, Ars, Acs, Azs, Aps, Bh, Bl, Brs, Bcs, Bzs, Bps,
                       C, Ch, Cl, Crs, Ccs, Czs, Cps, bias, biasN, zscale, resid, zp,
                       M, N, K, Zin, flags);
}

extern "C" void kernel_launch(void* const* d_in, const int* in_sizes, int n_in,
                              void* d_out, int out_size, void* d_ws, size_t ws_size,
                              hipStream_t stream)
{
    const float* x      = (const float*)d_in[0];
    const float* w_enc  = (const float*)d_in[1];
    const float* b_enc  = (const float*)d_in[2];
    const float* pos    = (const float*)d_in[3];
    const float* w_spec = (const float*)d_in[4];
    const float* b_spec = (const float*)d_in[5];
    const float* w_is   = (const float*)d_in[6];
    const float* b_is   = (const float*)d_in[7];
    const float* w_f1   = (const float*)d_in[8];
    const float* b_f1   = (const float*)d_in[9];
    const float* w_f2   = (const float*)d_in[10];
    const float* b_f2   = (const float*)d_in[11];
    const float* w_dec  = (const float*)d_in[12];
    const float* b_dec  = (const float*)d_in[13];
    float* out = (float*)d_out;

    // ---- workspace layout (bytes); total ~451 MB ----
    char* base = (char*)d_ws;
    size_t off = 0;
    auto alloc = [&](size_t bytes) { size_t o = off; off += (bytes + 255) & ~(size_t)255; return o; };
    u16* Pah = (u16*)(base + alloc(12056048));   // 181*33304 u16
    u16* Pal = (u16*)(base + alloc(12056048));
    u16* Psh = (u16*)(base + alloc(12056048));
    u16* Psl = (u16*)(base + alloc(12056048));
    u16* Eh  = (u16*)(base + alloc(260640));     // 2*PIX u16
    u16* El  = (u16*)(base + alloc(260640));
    u16* DtTh = (u16*)(base + alloc(276480));    // 360*384 u16
    u16* DtTl = (u16*)(base + alloc(276480));
    float* wqs = (float*)(base + alloc(724));
    u16* zp  = (u16*)(base + alloc(256));        // 16B zero page (k-tail source)
    // spectral bf16 pair bufs, ONE contiguous block (hmlpT overlay needs contiguity)
    u16* SP  = (u16*)(base + alloc(134189056));  // 4 * PLANE-pair u16 regions
    u16* S0h = SP;
    u16* S0l = SP + 16773632;
    u16* S1h = SP + 2 * 16773632;
    u16* S1l = SP + 3 * 16773632;
    u16* hmlpTh = SP;                    // [PIX][512] u16, spectral bufs dead by MLP time
    u16* hmlpTl = SP + 33361920;
    float* xn  = (float*)(base + alloc(66723840));   // fp32 [c][p] (fc2 residual)
    u16* xnTh = (u16*)(base + alloc(33361920));      // transposed pair [p][c]
    u16* xnTl = (u16*)(base + alloc(33361920));
    float* hbuf = (float*)(base + alloc(66723840));
    float* tA   = (float*)(base + alloc(66723840));
    u16* wth = (u16*)tA;                 // wt pair overlays tA; dead once iDFT writes tA
    u16* wtl = wth + 11862016;           // 181*65536
    u16* wish = (u16*)(base + alloc(131072));
    u16* wisl = (u16*)(base + alloc(131072));
    u16* wf1h = (u16*)(base + alloc(262144));
    u16* wf1l = (u16*)(base + alloc(262144));
    u16* wf2h = (u16*)(base + alloc(262144));
    u16* wf2l = (u16*)(base + alloc(262144));

    init_legendre<<<(181 * 181 + 255) / 256, 256, 0, stream>>>(Pah, Pal, Psh, Psl);
    init_trig<<<(181 * 360 + 255) / 256, 256, 0, stream>>>(Eh, El, DtTh, DtTl, wqs, zp);

    // encoder: h = w_enc*x + b_enc + pos_emb  (K=26, memory-bound: keep fp32 GEMM)
    launch_gemm(stream, w_enc, 26, 1, 0, 0,  x, PIXg, 1, 0, 0,  hbuf, PIXg, 1, 0, 0,
                b_enc, nullptr, pos, EMBg, PIXg, 26, 1, 1, 0);

    for (int L = 0; L < 4; ++L) {
        const float* wsp = w_spec + (size_t)L * EMBg * EMBg * 181;
        const float* bsp = b_spec + (size_t)L * EMBg;
        const float* wis = w_is   + (size_t)L * EMBg * EMBg;
        const float* bis = b_is   + (size_t)L * EMBg;
        const float* wf1 = w_f1   + (size_t)L * MHIDg * EMBg;
        const float* bf1 = b_f1   + (size_t)L * MHIDg;
        const float* wf2 = w_f2   + (size_t)L * EMBg * MHIDg;
        const float* bf2 = b_f2   + (size_t)L * EMBg;

        transpose_wspec<<<dim3(6, 8, 256), 256, 0, stream>>>(wsp, wth, wtl);
        split_bf16<<<(65536 + 255) / 256, 256, 0, stream>>>(wis, wish, wisl, 65536);
        split_bf16<<<(131072 + 255) / 256, 256, 0, stream>>>(wf1, wf1h, wf1l, 131072);
        split_bf16<<<(131072 + 255) / 256, 256, 0, stream>>>(wf2, wf2h, wf2l, 131072);

        // xn = LN(h): fp32 [c][p] + transposed pair [p][c]
        ln_kernel<<<1019, 256, 0, stream>>>(hbuf, xn, xnTh, xnTl);

        // DFT (z=lat k, planes cos/sin): S0[m][k][c] = (sum_n E[m][n]*xnT[k*360+n][c])*wqs[k]
        // A=E: G (k=n contig). B=xnT: R (panel contiguous).
        launch_gemm16(stream, Eh, El, 360, 1, 0, PIXg,  xnTh, xnTl, 256, 1, 92160, 0,
                      nullptr, S0h, S0l, 46336, 1, 256, PLANEg,
                      nullptr, nullptr, wqs, nullptr, zp, 181, 256, 360, 181, 2, FLAG_BF16);
        // analysis (z=m): S1[l][m][c] = sum_k Pa[m][l][k]*S0[m][k][c]
        // A=Pa: G. B=S0: R (contiguous 92KB panel per z).
        launch_gemm16(stream, Pah, Pal, PKSTR, 1, PMSTR2, 0,  S0h, S0l, 256, 1, 46336, PLANEg,
                      nullptr, S1h, S1l, 46336, 1, 256, PLANEg,
                      nullptr, nullptr, nullptr, nullptr, zp, 181, 256, 181, 181, 2, FLAG_BF16);
        // dhconv (z=l): S0'[m][l][o] = sum_i S1[l][m][i]*wt[l][i][o]
        // A=S1: G (k=i contig). B=wt: R (contiguous 128KB panel per z).
        launch_gemm16(stream, S1h, S1l, 256, 1, 46336, PLANEg,  wth, wtl, 256, 1, 65536, 0,
                      nullptr, S0h, S0l, 46336, 1, 256, PLANEg,
                      nullptr, nullptr, nullptr, nullptr, zp, 181, 256, 256, 181, 2, FLAG_BF16);
        // synthesis (z=m): S1'[k][pl*181+m][c] = sum_l Ps[m][k][l]*S0'[m][l][c]
        // A=Ps: G. B=S0': R (contiguous panel).
        launch_gemm16(stream, Psh, Psl, PKSTR, 1, PMSTR2, 0,  S0h, S0l, 256, 1, 46336, PLANEg,
                      nullptr, S1h, S1l, 92672, 1, 256, 46336,
                      nullptr, nullptr, nullptr, nullptr, zp, 181, 256, 181, 181, 2, FLAG_BF16);
        // iDFT (z=lat k): tA[c][k*360+n] = sum_{m'} S1'[k][m'][c]*DtT[n][m']
        // A=S1': R (contiguous 185KB panel per z). B=DtT: G (k=m' contig, 384-padded).
        launch_gemm16(stream, S1h, S1l, 1, 256, 92672, 0,  DtTh, DtTl, 1, 384, 0, 0,
                      tA, nullptr, nullptr, PIXg, 1, 360, 0,
                      nullptr, nullptr, nullptr, nullptr, zp, 256, 360, 362, 181, 1, FLAG_F32);
        // inner skip into tA: tA += wis*xn + bis   (A: G; B=xnT: G)
        launch_gemm16(stream, wish, wisl, 256, 1, 0, 0,  xnTh, xnTl, 1, 256, 0, 0,
                      tA, nullptr, nullptr, PIXg, 1, 0, 0,
                      bis, nullptr, nullptr, nullptr, zp, 256, PIXg, 256, 1, 1, FLAG_F32 | FLAG_ACC);
        // x1 = gelu(tA + b_spec) in place
        gelu_bias<<<16290, 256, 0, stream>>>(tA, bsp);
        // x2 = LN(x1): transposed pair only (fc1 consumes [p][c]); xn fp32 preserved
        ln_kernel<<<1019, 256, 0, stream>>>(tA, nullptr, xnTh, xnTl);
        // fc1 TRANSPOSED: hmlpT[p][h] = gelu(sum_i xnT[p][i]*wf1[h][i] + bf1[h])
        // M=PIX rows p, N=512 cols h, col-bias bf1. A=xnT: G; B=wf1: G.
        launch_gemm16(stream, xnTh, xnTl, 256, 1, 0, 0,  wf1h, wf1l, 1, 256, 0, 0,
                      nullptr, hmlpTh, hmlpTl, 512, 1, 0, 0,
                      nullptr, bf1, nullptr, nullptr, zp, PIXg, 512, 256, 1, 1, FLAG_BF16 | FLAG_GELU);
        // fc2 + residual xn -> h: hbuf[c][p] = sum_h wf2[c][h]*hmlpT[p][h] + bf2 + xn
        // A=wf2: G; B=hmlpT: G.
        launch_gemm16(stream, wf2h, wf2l, 512, 1, 0, 0,  hmlpTh, hmlpTl, 1, 512, 0, 0,
                      hbuf, nullptr, nullptr, PIXg, 1, 0, 0,
                      bf2, nullptr, nullptr, xn, zp, EMBg, PIXg, 512, 1, 1, FLAG_F32);
    }

    // decoder: out = w_dec[:, :256]*h + w_dec[:, 256:]*x + b_dec  (tiny M: fp32 GEMM)
    launch_gemm(stream, w_dec, 282, 1, 0, 0,  hbuf, PIXg, 1, 0, 0,  out, PIXg, 1, 0, 0,
                b_dec, nullptr, nullptr, 26, PIXg, 256, 1, 1, 0);
    launch_gemm(stream, w_dec + 256, 282, 1, 0, 0,  x, PIXg, 1, 0, 0,  out, PIXg, 1, 0, 0,
                nullptr, nullptr, nullptr, 26, PIXg, 26, 1, 1, FLAG_ACC);
}